// Round 9
// baseline (1092.011 us; speedup 1.0000x reference)
//
#include <hip/hip_runtime.h>
#include <hip/hip_bf16.h>
#include <math.h>

#define NTOK 196
#define NDIM 768
#define NB 64
#define NH 12
#define NA 197               // N+1
#define MAT (NTOK * NTOK)    // 38416
#define ATTN_HW (NA * NA)    // 38809
#define POLAR_ITERS 15

// fused polar constants
#define PADC 208             // 13*16 padded cols/K for MFMA tiling
#define NTILE 13
// two buffers [196][208] bf16 = 163072 B (fits 160 KiB LDS)
#define POLAR_LDS_BYTES (2 * NTOK * PADC * 2)

// ---- MFMA gram constants ----
#define GCH 64               // K-chunk
#define GPLANE (208 * GCH)   // shorts per plane (rows padded to 208)
#define GRAM_LDS_BYTES (2 * GPLANE * 2)   // hi + lo planes = 53248 B
// fused gram+center: G staged in LDS as fp32 [196][GC_LD] (aliases staging planes)
#define GC_LD 200
#define GC_LDS_BYTES (NTOK * GC_LD * 4)   // 156800 B (+ ~3.6 KB static, fits 160 KiB)

// ---- MFMA F constants (F = Lp^T Lq via LT rows, NT form) ----
#define FCH 64               // K-chunk (K padded 196 -> 256, 4 chunks)
#define FA_ROWS 208          // A rows (output i, padded)
#define FB_ROWS 112          // B rows per column-half (7 tiles x 16)
#define FAPLANE (FA_ROWS * FCH)
#define FBPLANE (FB_ROWS * FCH)
#define FMF_LDS_BYTES ((2 * FAPLANE + 2 * FBPLANE) * 2)   // 81920 B

// ---- MFMA polish constants ----
#define HCH 64
#define HPLANE (208 * HCH)
#define H_LDS_BYTES (2 * HPLANE * 2)                      // 53248 B
#define NS_SCR_BYTES (8 * 16 * 17 * 4)                    // per-wave transpose scratch
#define NS_LDS_BYTES (FMF_LDS_BYTES + NS_SCR_BYTES)       // 90624 B

// ---- LDS power-iteration constants ----
#define POW_LD 197
#define POW_F_WORDS (NTOK * POW_LD)                       // 38612
#define POW_LDS_BYTES ((POW_F_WORDS + 2 * NTOK + 256) * 4) // 157040 B

// ---- panel-blocked Cholesky LDS layout (words) ----
#define PTLD 208                          // padded trailing-row dim for Pt
#define TRI_WORDS 19306                   // 196*197/2
#define CHOL2_PT_WORDS (16 * PTLD)        // 3328  (16B-aligned rows)
#define CHOL2_TRI_OFF CHOL2_PT_WORDS      // 3328
#define CHOL2_ROWOFF_OFF (CHOL2_TRI_OFF + TRI_WORDS)   // 22634
#define CHOL2_PV_OFF 22832                // padded to 16B alignment
#define CHOL2_LDS_BYTES ((CHOL2_PV_OFF + 32) * 4)      // 91456 B

typedef __attribute__((ext_vector_type(8))) short short8;
typedef __attribute__((ext_vector_type(4))) short short4_t;
typedef __attribute__((ext_vector_type(4))) float f32x4;

__device__ inline short8 s8zero() { short8 z = {0,0,0,0,0,0,0,0}; return z; }

__device__ inline short f2bf(float f) {            // RNE fp32 -> bf16
  union { float f; unsigned u; } v; v.f = f;
  unsigned u = v.u;
  u += 0x7fffu + ((u >> 16) & 1u);
  return (short)(u >> 16);
}
__device__ inline float bf2f(short s) {
  union { unsigned u; float f; } v;
  v.u = ((unsigned)(unsigned short)s) << 16;
  return v.f;
}

// ---------------- w: CLS->patch attention, head-mean, normalized ----------------
__global__ void k_w(const float* __restrict__ attn, float* __restrict__ wbuf) {
  int b = blockIdx.x;
  int tid = threadIdx.x;
  __shared__ float red[256];
  float w0 = 0.f;
  if (tid < NTOK) {
    size_t base = (size_t)b * NH * ATTN_HW + 1 + tid;
    #pragma unroll
    for (int h = 0; h < NH; ++h) w0 += attn[base + (size_t)h * ATTN_HW];
    w0 *= (1.f / NH);
  }
  red[tid] = (tid < NTOK) ? w0 : 0.f;
  __syncthreads();
  for (int s = 128; s > 0; s >>= 1) { if (tid < s) red[tid] += red[tid + s]; __syncthreads(); }
  float S = red[0];
  if (tid < NTOK) wbuf[b * NTOK + tid] = w0 / (S + 1e-8f);
}

// ---------------- FUSED: Gram (split-bf16 MFMA) + double-center + ridge + trace ----------------
// One block per slot.  After the K-loop the full G lives in this block's
// accumulators; stage G into LDS fp32 [196][GC_LD] (reusing the bf16 staging
// allocation), compute column means / grand mean / trace / ridge in-LDS, and
// write the CENTERED G to global.  Saves the k_center launch + a 300 KB/matrix
// global RMW round trip.  Arithmetic matches k_center (same column summation
// order, same centering expression).
__global__ __launch_bounds__(512, 1) void k_gramc(
    const float* __restrict__ s, const float* __restrict__ t,
    const float* __restrict__ wbuf, float* __restrict__ Gbuf,
    float* __restrict__ trPb) {
  extern __shared__ short gsm[];
  short* bhp = gsm;              // hi plane [208][GCH]
  short* blp = gsm + GPLANE;     // lo plane
  float* Gsh = (float*)gsm;      // reused AFTER the K-loop: [196][GC_LD] fp32
  __shared__ float wsh[NTOK];
  __shared__ float rr[NTOK];
  __shared__ float red2[512];
  __shared__ float gg_s, dd_s;
  int slot = blockIdx.x, b = slot >> 1, src = slot & 1;
  const float* X = (src ? t : s) + (size_t)b * NTOK * NDIM;
  int tid = threadIdx.x;
  int wave = tid >> 6, ln15 = tid & 15, quad = (tid >> 4) & 3;

  if (tid < NTOK) wsh[tid] = wbuf[b * NTOK + tid];
  // zero pad rows 196..207 of both planes (never written by staging)
  for (int i = tid; i < 768; i += 512) {          // 768 ints = 1536 shorts
    int p = i / 384, o = i - p * 384;
    ((int*)(gsm + p * GPLANE + 196 * GCH))[o] = 0;
  }
  __syncthreads();

  f32x4 zz = {0.f, 0.f, 0.f, 0.f};
  f32x4 acc[12];
  #pragma unroll
  for (int j = 0; j < 12; ++j) acc[j] = zz;

  for (int c = 0; c < NDIM / GCH; ++c) {
    int kc = c * GCH;
    // ---- stage chunk: Y hi/lo, granule-swizzled ----
    for (int gi = tid; gi < NTOK * 8; gi += 512) {
      int r = gi >> 3, g = gi & 7;
      const float* sp = X + (size_t)r * NDIM + kc + g * 8;
      float4 f0 = *(const float4*)(sp);
      float4 f1 = *(const float4*)(sp + 4);
      float wv = wsh[r];
      float vs[8] = {f0.x, f0.y, f0.z, f0.w, f1.x, f1.y, f1.z, f1.w};
      short8 hv, lv;
      #pragma unroll
      for (int e = 0; e < 8; ++e) {
        float y = wv * vs[e];
        short hb = f2bf(y);
        hv[e] = hb;
        lv[e] = f2bf(y - bf2f(hb));
      }
      int pg = (g ^ (r & 7)) * 8;
      *(short8*)(bhp + r * GCH + pg) = hv;
      *(short8*)(blp + r * GCH + pg) = lv;
    }
    __syncthreads();
    // ---- MFMA over this wave's lower-triangle tiles ----
    #pragma unroll
    for (int j = 0; j < 12; ++j) {
      int T = wave + 8 * j;
      if (T < 91) {
        int ti = (int)((sqrtf(8.f * T + 1.f) - 1.f) * 0.5f);
        if ((ti + 1) * (ti + 2) / 2 <= T) ++ti;
        if (ti * (ti + 1) / 2 > T) --ti;
        int tj = T - ti * (ti + 1) / 2;
        int ra = ti * 16 + ln15, rb = tj * 16 + ln15;
        #pragma unroll
        for (int ks = 0; ks < 2; ++ks) {
          int gb0 = ks * 4 + quad;
          int ga = (gb0 ^ (ra & 7)) * 8, gb = (gb0 ^ (rb & 7)) * 8;
          short8 ah = *(const short8*)(bhp + ra * GCH + ga);
          short8 al = *(const short8*)(blp + ra * GCH + ga);
          short8 bhf = *(const short8*)(bhp + rb * GCH + gb);
          short8 blf = *(const short8*)(blp + rb * GCH + gb);
          acc[j] = __builtin_amdgcn_mfma_f32_16x16x32_bf16(ah, bhf, acc[j], 0, 0, 0);
          acc[j] = __builtin_amdgcn_mfma_f32_16x16x32_bf16(ah, blf, acc[j], 0, 0, 0);
          acc[j] = __builtin_amdgcn_mfma_f32_16x16x32_bf16(al, bhf, acc[j], 0, 0, 0);
        }
      }
    }
    __syncthreads();
  }

  // ---- stage G (both symmetric halves) into LDS fp32 ----
  #pragma unroll
  for (int j = 0; j < 12; ++j) {
    int T = wave + 8 * j;
    if (T < 91) {
      int ti = (int)((sqrtf(8.f * T + 1.f) - 1.f) * 0.5f);
      if ((ti + 1) * (ti + 2) / 2 <= T) ++ti;
      if (ti * (ti + 1) / 2 > T) --ti;
      int tj = T - ti * (ti + 1) / 2;
      int col = tj * 16 + ln15;
      #pragma unroll
      for (int r = 0; r < 4; ++r) {
        int row = ti * 16 + quad * 4 + r;
        if (row < NTOK && col < NTOK) {
          Gsh[row * GC_LD + col] = acc[j][r];
          if (ti != tj) Gsh[col * GC_LD + row] = acc[j][r];
        }
      }
    }
  }
  __syncthreads();

  // ---- column means (lane-consecutive reads, conflict-free) ----
  float a0 = 0.f;
  if (tid < NTOK) {
    for (int m = 0; m < NTOK; ++m) a0 += Gsh[m * GC_LD + tid];
    rr[tid] = a0 * (1.f / NTOK);
  }
  red2[tid] = (tid < NTOK) ? a0 * (1.f / NTOK) : 0.f;
  __syncthreads();
  for (int st = 256; st > 0; st >>= 1) { if (tid < st) red2[tid] += red2[tid + st]; __syncthreads(); }
  float g = red2[0] * (1.f / NTOK);
  float tv = (tid < NTOK) ? (Gsh[tid * GC_LD + tid] - 2.f * rr[tid] + g) : 0.f;
  __syncthreads();
  red2[tid] = tv;
  __syncthreads();
  for (int st = 256; st > 0; st >>= 1) { if (tid < st) red2[tid] += red2[tid + st]; __syncthreads(); }
  if (tid == 0) {
    float tr = red2[0];
    trPb[slot] = tr;
    gg_s = g;
    dd_s = 1e-4f * fmaxf(tr, 0.f) * (1.f / NTOK);
  }
  __syncthreads();
  float gv = gg_s, dv = dd_s;

  // ---- centered writeback (vector float4 global stores) ----
  float* G = Gbuf + (size_t)slot * MAT;
  for (int q = tid; q < MAT / 4; q += 512) {
    int idx = q * 4;
    int n = idx / NTOK, m = idx - n * NTOK;
    float rn = rr[n];
    float v0 = Gsh[n * GC_LD + m + 0] - rn - rr[m + 0] + gv;
    float v1 = Gsh[n * GC_LD + m + 1] - rn - rr[m + 1] + gv;
    float v2 = Gsh[n * GC_LD + m + 2] - rn - rr[m + 2] + gv;
    float v3 = Gsh[n * GC_LD + m + 3] - rn - rr[m + 3] + gv;
    if (n == m) v0 += dv;
    else if (n == m + 1) v1 += dv;
    else if (n == m + 2) v2 += dv;
    else if (n == m + 3) v3 += dv;
    float4 o = {v0, v1, v2, v3};
    ((float4*)G)[q] = o;
  }
}

// ---------------- fallback Gram via split-bf16 MFMA (no centering) ----------------
__global__ __launch_bounds__(512, 1) void k_gram_mfma(
    const float* __restrict__ s, const float* __restrict__ t,
    const float* __restrict__ wbuf, float* __restrict__ Gbuf) {
  extern __shared__ short gsm[];
  short* bhp = gsm;              // hi plane [208][GCH]
  short* blp = gsm + GPLANE;     // lo plane
  __shared__ float wsh[NTOK];
  int slot = blockIdx.x, b = slot >> 1, src = slot & 1;
  const float* X = (src ? t : s) + (size_t)b * NTOK * NDIM;
  int tid = threadIdx.x;
  int wave = tid >> 6, ln15 = tid & 15, quad = (tid >> 4) & 3;

  if (tid < NTOK) wsh[tid] = wbuf[b * NTOK + tid];
  for (int i = tid; i < 768; i += 512) {
    int p = i / 384, o = i - p * 384;
    ((int*)(gsm + p * GPLANE + 196 * GCH))[o] = 0;
  }
  __syncthreads();

  f32x4 zz = {0.f, 0.f, 0.f, 0.f};
  f32x4 acc[12];
  #pragma unroll
  for (int j = 0; j < 12; ++j) acc[j] = zz;

  for (int c = 0; c < NDIM / GCH; ++c) {
    int kc = c * GCH;
    for (int gi = tid; gi < NTOK * 8; gi += 512) {
      int r = gi >> 3, g = gi & 7;
      const float* sp = X + (size_t)r * NDIM + kc + g * 8;
      float4 f0 = *(const float4*)(sp);
      float4 f1 = *(const float4*)(sp + 4);
      float wv = wsh[r];
      float vs[8] = {f0.x, f0.y, f0.z, f0.w, f1.x, f1.y, f1.z, f1.w};
      short8 hv, lv;
      #pragma unroll
      for (int e = 0; e < 8; ++e) {
        float y = wv * vs[e];
        short hb = f2bf(y);
        hv[e] = hb;
        lv[e] = f2bf(y - bf2f(hb));
      }
      int pg = (g ^ (r & 7)) * 8;
      *(short8*)(bhp + r * GCH + pg) = hv;
      *(short8*)(blp + r * GCH + pg) = lv;
    }
    __syncthreads();
    #pragma unroll
    for (int j = 0; j < 12; ++j) {
      int T = wave + 8 * j;
      if (T < 91) {
        int ti = (int)((sqrtf(8.f * T + 1.f) - 1.f) * 0.5f);
        if ((ti + 1) * (ti + 2) / 2 <= T) ++ti;
        if (ti * (ti + 1) / 2 > T) --ti;
        int tj = T - ti * (ti + 1) / 2;
        int ra = ti * 16 + ln15, rb = tj * 16 + ln15;
        #pragma unroll
        for (int ks = 0; ks < 2; ++ks) {
          int gb0 = ks * 4 + quad;
          int ga = (gb0 ^ (ra & 7)) * 8, gb = (gb0 ^ (rb & 7)) * 8;
          short8 ah = *(const short8*)(bhp + ra * GCH + ga);
          short8 al = *(const short8*)(blp + ra * GCH + ga);
          short8 bhf = *(const short8*)(bhp + rb * GCH + gb);
          short8 blf = *(const short8*)(blp + rb * GCH + gb);
          acc[j] = __builtin_amdgcn_mfma_f32_16x16x32_bf16(ah, bhf, acc[j], 0, 0, 0);
          acc[j] = __builtin_amdgcn_mfma_f32_16x16x32_bf16(ah, blf, acc[j], 0, 0, 0);
          acc[j] = __builtin_amdgcn_mfma_f32_16x16x32_bf16(al, bhf, acc[j], 0, 0, 0);
        }
      }
    }
    __syncthreads();
  }

  float* G = Gbuf + (size_t)slot * MAT;
  #pragma unroll
  for (int j = 0; j < 12; ++j) {
    int T = wave + 8 * j;
    if (T < 91) {
      int ti = (int)((sqrtf(8.f * T + 1.f) - 1.f) * 0.5f);
      if ((ti + 1) * (ti + 2) / 2 <= T) ++ti;
      if (ti * (ti + 1) / 2 > T) --ti;
      int tj = T - ti * (ti + 1) / 2;
      int col = tj * 16 + ln15;
      #pragma unroll
      for (int r = 0; r < 4; ++r) {
        int row = ti * 16 + quad * 4 + r;
        if (row < NTOK && col < NTOK) {
          G[row * NTOK + col] = acc[j][r];
          if (ti != tj) G[col * NTOK + row] = acc[j][r];
        }
      }
    }
  }
}

// ---------------- double-center in place (fallback path) ----------------
__global__ void k_center(float* __restrict__ Gbuf, float* __restrict__ trPb) {
  int slot = blockIdx.x;
  float* A = Gbuf + (size_t)slot * MAT;
  __shared__ float r[NTOK];
  __shared__ float red[256];
  __shared__ float gsh, dsh;
  int tid = threadIdx.x;
  float acc = 0.f;
  if (tid < NTOK) {
    for (int m = 0; m < NTOK; ++m) acc += A[m * NTOK + tid];
    r[tid] = acc * (1.f / NTOK);
  }
  red[tid] = (tid < NTOK) ? acc * (1.f / NTOK) : 0.f;
  __syncthreads();
  for (int s = 128; s > 0; s >>= 1) { if (tid < s) red[tid] += red[tid + s]; __syncthreads(); }
  float g = red[0] * (1.f / NTOK);
  float tv = (tid < NTOK) ? (A[tid * NTOK + tid] - 2.f * r[tid] + g) : 0.f;
  __syncthreads();
  red[tid] = tv;
  __syncthreads();
  for (int s = 128; s > 0; s >>= 1) { if (tid < s) red[tid] += red[tid + s]; __syncthreads(); }
  if (tid == 0) {
    float tr = red[0];
    trPb[slot] = tr;
    gsh = g;
    dsh = 1e-4f * fmaxf(tr, 0.f) * (1.f / NTOK);
  }
  __syncthreads();
  float gg = gsh, dd = dsh;
  for (int idx = tid; idx < MAT; idx += 256) {
    int n = idx / NTOK, m = idx - n * NTOK;
    float v = A[idx] - r[n] - r[m] + gg;
    if (n == m) v += dd;
    A[idx] = v;
  }
}

// ---------------- panel-blocked (NB=16) Cholesky, triangle-packed LDS ----------------
// transposeOut != 0: write back L^T for the MFMA k_F consumer.
__global__ __launch_bounds__(256, 1) void k_chol_panel(float* __restrict__ Gbuf,
                                                       int transposeOut) {
  extern __shared__ float smf[];
  float* Pt = smf;                              // [16][PTLD]
  float* tri = smf + CHOL2_TRI_OFF;             // TRI_WORDS
  int* rowoff = (int*)(smf + CHOL2_ROWOFF_OFF); // [196]
  float* pvb = smf + CHOL2_PV_OFF;              // [2][16], 16B aligned
  int slot = blockIdx.x;
  float* A = Gbuf + (size_t)slot * MAT;
  int tid = threadIdx.x;
  if (tid < NTOK) rowoff[tid] = tid * (tid + 1) / 2;
  __syncthreads();
  // load lower triangle
  for (int idx = tid; idx < MAT; idx += 256) {
    int i = idx / NTOK, j = idx - i * NTOK;
    if (j <= i) tri[rowoff[i] + j] = A[idx];
  }
  __syncthreads();

  for (int k0 = 0; k0 < NTOK; k0 += 16) {
    int nb = (NTOK - k0 < 16) ? (NTOK - k0) : 16;
    int t = tid;
    int i = k0 + t;
    bool hasrow = (t < NTOK - k0);
    int ro = hasrow ? rowoff[i] : 0;

    float a[16];
    #pragma unroll
    for (int jj = 0; jj < 16; ++jj) a[jj] = 0.f;
    if (hasrow) {
      #pragma unroll
      for (int jj = 0; jj < 16; ++jj)
        if (jj < nb && k0 + jj <= i) a[jj] = tri[ro + k0 + jj];
    }

    #pragma unroll
    for (int jj = 0; jj < 16; ++jj) {
      bool cv = (jj < nb);
      if (cv && hasrow && t >= jj && t < nb) pvb[((jj & 1) << 4) + t] = a[jj];
      __syncthreads();
      if (cv && hasrow && t >= jj) {
        const float* pv = pvb + ((jj & 1) << 4);
        f32x4 p0 = *(const f32x4*)(pv);
        f32x4 p1 = *(const f32x4*)(pv + 4);
        f32x4 p2 = *(const f32x4*)(pv + 8);
        f32x4 p3 = *(const f32x4*)(pv + 12);
        float pvj = (jj < 4) ? p0[jj & 3] : (jj < 8) ? p1[jj & 3]
                   : (jj < 12) ? p2[jj & 3] : p3[jj & 3];
        float sq = sqrtf(fmaxf(pvj, 1e-20f));
        float pivinv = 1.f / sq;
        float v = a[jj] * pivinv;
        a[jj] = v;
        #pragma unroll
        for (int m = 0; m < 16; ++m) {
          if (m > jj) {
            float pvm = (m < 4) ? p0[m & 3] : (m < 8) ? p1[m & 3]
                       : (m < 12) ? p2[m & 3] : p3[m & 3];
            if (m < nb) a[m] -= v * (pvm * pivinv);
          }
        }
      }
    }

    if (hasrow) {
      #pragma unroll
      for (int jj = 0; jj < 16; ++jj)
        if (jj < nb && k0 + jj <= i) tri[ro + k0 + jj] = a[jj];
      if (t >= nb) {
        #pragma unroll
        for (int jj = 0; jj < 16; ++jj)
          if (jj < nb) Pt[jj * PTLD + i] = a[jj];
      }
    }
    __syncthreads();

    int k1 = k0 + nb;
    int nrem = NTOK - k1;
    if (nrem > 0) {
      int ntile = (nrem + 3) >> 2;
      int Ttot = ntile * (ntile + 1) / 2;
      for (int T = tid; T < Ttot; T += 256) {
        float disc = (2.f * ntile + 1.f) * (2.f * ntile + 1.f) - 8.f * (float)T;
        int tm = (int)((2.f * ntile + 1.f - sqrtf(fmaxf(disc, 0.f))) * 0.5f);
        if (tm > ntile - 1) tm = ntile - 1;
        if (tm < 0) tm = 0;
        #define FCOL(c) ((c) * ntile - (((c) * ((c) - 1)) >> 1))
        while (tm + 1 <= ntile - 1 && FCOL(tm + 1) <= T) ++tm;
        while (tm > 0 && FCOL(tm) > T) --tm;
        int ti = tm + (T - FCOL(tm));
        #undef FCOL
        int i0 = k1 + ti * 4, m0 = k1 + tm * 4;
        f32x4 acc0 = {0.f, 0.f, 0.f, 0.f};
        f32x4 acc1 = acc0, acc2 = acc0, acc3 = acc0;
        #pragma unroll
        for (int jj = 0; jj < 16; ++jj) {
          if (jj < nb) {
            f32x4 li = *(const f32x4*)(Pt + jj * PTLD + i0);
            f32x4 lm = *(const f32x4*)(Pt + jj * PTLD + m0);
            acc0 += lm * li[0];
            acc1 += lm * li[1];
            acc2 += lm * li[2];
            acc3 += lm * li[3];
          }
        }
        #define STORE_ROW(r, av)                                        \
          { int ii = i0 + (r);                                          \
            if (ii < NTOK) {                                            \
              int roi = rowoff[ii];                                     \
              if (m0 + 0 <= ii) tri[roi + m0 + 0] -= (av)[0];           \
              if (m0 + 1 <= ii) tri[roi + m0 + 1] -= (av)[1];           \
              if (m0 + 2 <= ii) tri[roi + m0 + 2] -= (av)[2];           \
              if (m0 + 3 <= ii) tri[roi + m0 + 3] -= (av)[3];           \
            } }
        STORE_ROW(0, acc0)
        STORE_ROW(1, acc1)
        STORE_ROW(2, acc2)
        STORE_ROW(3, acc3)
        #undef STORE_ROW
      }
    }
    __syncthreads();
  }

  if (transposeOut) {
    for (int idx = tid; idx < MAT; idx += 256) {
      int r2 = idx / NTOK, c2 = idx - r2 * NTOK;
      A[idx] = (r2 <= c2) ? tri[rowoff[c2] + r2] : 0.f;
    }
  } else {
    for (int idx = tid; idx < MAT; idx += 256) {
      int i = idx / NTOK, j = idx - i * NTOK;
      A[idx] = (j <= i) ? tri[rowoff[i] + j] : 0.f;
    }
  }
}

// ---------------- fallback: original global-memory Cholesky ----------------
__global__ void k_chol_global(float* __restrict__ Gbuf) {
  int slot = blockIdx.x;
  float* A = Gbuf + (size_t)slot * MAT;
  __shared__ float col[NTOK];
  __shared__ float piv;
  int tid = threadIdx.x;
  for (int k = 0; k < NTOK; ++k) {
    if (tid == 0) { float p = sqrtf(fmaxf(A[k * NTOK + k], 1e-20f)); A[k * NTOK + k] = p; piv = p; }
    __syncthreads();
    float inv = 1.f / piv;
    for (int i = k + 1 + tid; i < NTOK; i += 256) {
      float v = A[i * NTOK + k] * inv;
      A[i * NTOK + k] = v;
      col[i] = v;
    }
    for (int j = k + 1 + tid; j < NTOK; j += 256) A[k * NTOK + j] = 0.f;
    __syncthreads();
    int nrem = NTOK - 1 - k;
    int total = nrem * (nrem + 1) / 2;
    for (int tt = tid; tt < total; tt += 256) {
      int a = (int)((sqrtf(8.f * tt + 1.f) - 1.f) * 0.5f);
      while ((a + 1) * (a + 2) / 2 <= tt) ++a;
      while (a * (a + 1) / 2 > tt) --a;
      int bb = tt - a * (a + 1) / 2;
      int i = k + 1 + a, j = k + 1 + bb;
      A[i * NTOK + j] -= col[i] * col[j];
    }
    __syncthreads();
  }
}

// ---------------- F = Lp^T Lq via split-bf16 MFMA (inputs are L^T, NT form) ----------------
__global__ __launch_bounds__(512, 1) void k_F_mfma(const float* __restrict__ Gbuf,
                                                   float* __restrict__ Fbuf) {
  extern __shared__ short fsm[];
  short* Ah = fsm;
  short* Al = Ah + FAPLANE;
  short* Bh = Al + FAPLANE;
  short* Bl = Bh + FBPLANE;
  int half = blockIdx.x, b = blockIdx.y;
  const float* LTp = Gbuf + (size_t)(2 * b) * MAT;
  const float* LTq = Gbuf + (size_t)(2 * b + 1) * MAT;
  int co = half * 112;
  int tid = threadIdx.x;
  int wave = tid >> 6, ln15 = tid & 15, quad = (tid >> 4) & 3;

  f32x4 zz = {0.f, 0.f, 0.f, 0.f};
  f32x4 acc[12];
  #pragma unroll
  for (int j = 0; j < 12; ++j) acc[j] = zz;

  for (int c = 0; c < 4; ++c) {
    int kc = c * FCH;
    bool fullchunk = (kc + FCH <= NTOK);
    for (int gi = tid; gi < (FA_ROWS + FB_ROWS) * 8; gi += 512) {
      bool isA = gi < FA_ROWS * 8;
      int li = isA ? gi : gi - FA_ROWS * 8;
      int r = li >> 3, g = li & 7;
      int grow = isA ? r : co + r;
      short8 hv = s8zero(), lv = s8zero();
      if (grow < NTOK) {
        const float* src = (isA ? LTp : LTq) + (size_t)grow * NTOK + kc + g * 8;
        if (fullchunk) {
          float4 f0 = *(const float4*)(src);
          float4 f1 = *(const float4*)(src + 4);
          float vs[8] = {f0.x, f0.y, f0.z, f0.w, f1.x, f1.y, f1.z, f1.w};
          #pragma unroll
          for (int e = 0; e < 8; ++e) {
            short hb = f2bf(vs[e]);
            hv[e] = hb;
            lv[e] = f2bf(vs[e] - bf2f(hb));
          }
        } else {
          #pragma unroll
          for (int e = 0; e < 8; ++e) {
            int k = kc + g * 8 + e;
            if (k < NTOK) {
              float y = src[e];
              short hb = f2bf(y);
              hv[e] = hb;
              lv[e] = f2bf(y - bf2f(hb));
            }
          }
        }
      }
      int pg = (g ^ (r & 7)) * 8;
      if (isA) {
        *(short8*)(Ah + r * FCH + pg) = hv;
        *(short8*)(Al + r * FCH + pg) = lv;
      } else {
        *(short8*)(Bh + r * FCH + pg) = hv;
        *(short8*)(Bl + r * FCH + pg) = lv;
      }
    }
    __syncthreads();
    #pragma unroll
    for (int j = 0; j < 12; ++j) {
      int T = wave + 8 * j;
      if (T < 91) {
        int ti = T / 7, tj = T - ti * 7;
        if (co + tj * 16 < NTOK) {
          int ra = ti * 16 + ln15;
          int rb = tj * 16 + ln15;
          #pragma unroll
          for (int ks = 0; ks < 2; ++ks) {
            int gb0 = ks * 4 + quad;
            int ga = (gb0 ^ (ra & 7)) * 8, gb = (gb0 ^ (rb & 7)) * 8;
            short8 ah = *(const short8*)(Ah + ra * FCH + ga);
            short8 al = *(const short8*)(Al + ra * FCH + ga);
            short8 bh = *(const short8*)(Bh + rb * FCH + gb);
            short8 bl = *(const short8*)(Bl + rb * FCH + gb);
            acc[j] = __builtin_amdgcn_mfma_f32_16x16x32_bf16(ah, bh, acc[j], 0, 0, 0);
            acc[j] = __builtin_amdgcn_mfma_f32_16x16x32_bf16(ah, bl, acc[j], 0, 0, 0);
            acc[j] = __builtin_amdgcn_mfma_f32_16x16x32_bf16(al, bh, acc[j], 0, 0, 0);
          }
        }
      }
    }
    __syncthreads();
  }

  float* F = Fbuf + (size_t)b * MAT;
  #pragma unroll
  for (int j = 0; j < 12; ++j) {
    int T = wave + 8 * j;
    if (T < 91) {
      int ti = T / 7, tj = T - ti * 7;
      int col = co + tj * 16 + ln15;
      if (col < NTOK) {
        #pragma unroll
        for (int r = 0; r < 4; ++r) {
          int row = ti * 16 + quad * 4 + r;
          if (row < NTOK) F[row * NTOK + col] = acc[j][r];
        }
      }
    }
  }
}

// ---------------- fallback F = Lp^T * Lq (scalar, reads L) ----------------
__global__ void k_F(const float* __restrict__ Gbuf, float* __restrict__ Fbuf) {
  int b = blockIdx.y;
  const float* Lp = Gbuf + (size_t)(2 * b) * MAT;
  const float* Lq = Gbuf + (size_t)(2 * b + 1) * MAT;
  int ti = blockIdx.x / 7, tj = blockIdx.x % 7;
  int ri = ti * 32, cj = tj * 32;
  __shared__ float As[32][33], Bs[32][33];
  int tid = threadIdx.x, ty = tid >> 4, tx = tid & 15;
  float a00 = 0, a01 = 0, a10 = 0, a11 = 0;
  for (int k0 = 0; k0 < NTOK; k0 += 32) {
    for (int l = tid; l < 1024; l += 256) {
      int kk = l >> 5, ii = l & 31;
      int krow = k0 + kk;
      As[kk][ii] = (krow < NTOK && ri + ii < NTOK) ? Lp[(size_t)krow * NTOK + ri + ii] : 0.f;
      Bs[kk][ii] = (krow < NTOK && cj + ii < NTOK) ? Lq[(size_t)krow * NTOK + cj + ii] : 0.f;
    }
    __syncthreads();
    #pragma unroll
    for (int kk = 0; kk < 32; ++kk) {
      float p0 = As[kk][ty], p1 = As[kk][ty + 16];
      float q0 = Bs[kk][tx], q1 = Bs[kk][tx + 16];
      a00 += p0 * q0; a01 += p0 * q1; a10 += p1 * q0; a11 += p1 * q1;
    }
    __syncthreads();
  }
  float* F = Fbuf + (size_t)b * MAT;
  int i0 = ri + ty, i1 = ri + ty + 16, j0 = cj + tx, j1 = cj + tx + 16;
  if (i0 < NTOK && j0 < NTOK) F[i0 * NTOK + j0] = a00;
  if (i0 < NTOK && j1 < NTOK) F[i0 * NTOK + j1] = a01;
  if (i1 < NTOK && j0 < NTOK) F[i1 * NTOK + j0] = a10;
  if (i1 < NTOK && j1 < NTOK) F[i1 * NTOK + j1] = a11;
}

// ---------------- power iteration from LDS: sigma_max -> 1/(1.1*sigma) ----------------
__global__ __launch_bounds__(256, 1) void k_pow_lds(const float* __restrict__ Fbuf,
                                                    float* __restrict__ nrmb) {
  extern __shared__ float psm[];
  float* Fsh = psm;                 // [196][197]
  float* v = psm + POW_F_WORDS;
  float* u = v + NTOK;
  float* red = u + NTOK;
  int b = blockIdx.x;
  const float* F = Fbuf + (size_t)b * MAT;
  int tid = threadIdx.x;
  for (int idx = tid; idx < MAT; idx += 256) {
    int i = idx / NTOK, j = idx - i * NTOK;
    Fsh[i * POW_LD + j] = F[idx];
  }
  if (tid < NTOK) v[tid] = 1.f;
  __syncthreads();
  float lastsum = 1.f;
  for (int it = 0; it < 6; ++it) {
    if (tid < NTOK) {
      float a = 0.f;
      for (int j = 0; j < NTOK; ++j) a += Fsh[tid * POW_LD + j] * v[j];
      u[tid] = a;
    }
    __syncthreads();
    float a2 = 0.f;
    if (tid < NTOK) { for (int i = 0; i < NTOK; ++i) a2 += Fsh[i * POW_LD + tid] * u[i]; }
    red[tid] = (tid < NTOK) ? a2 * a2 : 0.f;
    __syncthreads();
    for (int s2 = 128; s2 > 0; s2 >>= 1) { if (tid < s2) red[tid] += red[tid + s2]; __syncthreads(); }
    float sum = red[0];
    lastsum = sum;
    float invn = rsqrtf(sum + 1e-30f);
    __syncthreads();
    if (tid < NTOK) v[tid] = a2 * invn;
    __syncthreads();
  }
  if (tid == 0) {
    float sig = sqrtf(sqrtf(lastsum));
    nrmb[b] = 1.f / (1.1f * sig + 1e-30f);
  }
}

// ---------------- fallback power iteration (global) ----------------
__global__ void k_pow(const float* __restrict__ Fbuf, float* __restrict__ nrmb) {
  int b = blockIdx.x;
  const float* F = Fbuf + (size_t)b * MAT;
  __shared__ float v[NTOK], u[NTOK];
  __shared__ float red[256];
  int tid = threadIdx.x;
  if (tid < NTOK) v[tid] = 1.f;
  __syncthreads();
  float lastsum = 1.f;
  for (int it = 0; it < 6; ++it) {
    float a = 0.f;
    if (tid < NTOK) { for (int j = 0; j < NTOK; ++j) a += F[tid * NTOK + j] * v[j]; }
    __syncthreads();
    if (tid < NTOK) u[tid] = a;
    __syncthreads();
    float a2 = 0.f;
    if (tid < NTOK) { for (int i = 0; i < NTOK; ++i) a2 += F[i * NTOK + tid] * u[i]; }
    red[tid] = (tid < NTOK) ? a2 * a2 : 0.f;
    __syncthreads();
    for (int s = 128; s > 0; s >>= 1) { if (tid < s) red[tid] += red[tid + s]; __syncthreads(); }
    float sum = red[0];
    lastsum = sum;
    float invn = rsqrtf(sum + 1e-30f);
    __syncthreads();
    if (tid < NTOK) v[tid] = a2 * invn;
    __syncthreads();
  }
  if (tid == 0) {
    float sig = sqrtf(sqrtf(lastsum));
    nrmb[b] = 1.f / (1.1f * sig + 1e-30f);
  }
}

// ---------------- X0 = F * invnorm (fallback path only) ----------------
__global__ void k_scale(const float* __restrict__ Fbuf, const float* __restrict__ nrmb,
                        float* __restrict__ X) {
  int b = blockIdx.y;
  int idx = blockIdx.x * 256 + threadIdx.x;
  if (idx < MAT) X[(size_t)b * MAT + idx] = Fbuf[(size_t)b * MAT + idx] * nrmb[b];
}

// ---------------- fused bf16-MFMA polar Newton-Schulz loop (all-LDS) ----------------
// EXACT round-2 structure (best measured).  Do not restructure (r3/r4/r5 all lost).
__global__ __launch_bounds__(512, 1) void k_polar_fused(
    const float* __restrict__ Fbuf, const float* __restrict__ nrmb,
    float* __restrict__ Xout) {
  extern __shared__ short sm[];
  short* bufA = sm;                      // [196][PADC]  X
  short* bufB = sm + NTOK * PADC;        // [196][PADC]  H'
  int b = blockIdx.x;
  const float* F = Fbuf + (size_t)b * MAT;
  float* XO = Xout + (size_t)b * MAT;
  int tid = threadIdx.x;
  int wave = tid >> 6, ln15 = tid & 15, quad = (tid >> 4) & 3;
  int rt0 = wave, rt1 = wave + 8;
  bool has2 = (rt1 < NTILE);

  for (int i = tid; i < (2 * NTOK * PADC) / 2; i += 512) ((int*)sm)[i] = 0;
  __syncthreads();
  float invc = nrmb[b];
  for (int idx = tid; idx < MAT; idx += 512) {
    int i = idx / NTOK, j = idx - i * NTOK;
    bufA[i * PADC + j] = f2bf(F[idx] * invc);
  }
  __syncthreads();

  int arow0 = rt0 * 16 + ln15;
  int arow1 = rt1 * 16 + ln15;
  bool av1 = has2 && (arow1 < NTOK);
  int m0a = rt0 * 16 + quad * 4;
  int m1a = rt1 * 16 + quad * 4;

  for (int it = 0; it < POLAR_ITERS; ++it) {
    {
      short8 a0[7], a1[7];
      #pragma unroll
      for (int ks = 0; ks < 7; ++ks) {
        int kk = ks * 32 + quad * 8;
        a0[ks] = (kk < PADC) ? *(const short8*)(bufA + arow0 * PADC + kk) : s8zero();
        a1[ks] = (av1 && kk < PADC) ? *(const short8*)(bufA + arow1 * PADC + kk) : s8zero();
      }
      for (int ct = 0; ct < NTILE; ++ct) {
        int brow = ct * 16 + ln15;
        bool bv = brow < NTOK;
        f32x4 acc0 = {0.f, 0.f, 0.f, 0.f};
        f32x4 acc1 = {0.f, 0.f, 0.f, 0.f};
        #pragma unroll
        for (int ks = 0; ks < 7; ++ks) {
          int kk = ks * 32 + quad * 8;
          short8 bfr = (bv && kk < PADC) ? *(const short8*)(bufA + brow * PADC + kk) : s8zero();
          acc0 = __builtin_amdgcn_mfma_f32_16x16x32_bf16(a0[ks], bfr, acc0, 0, 0, 0);
          if (has2)
            acc1 = __builtin_amdgcn_mfma_f32_16x16x32_bf16(a1[ks], bfr, acc1, 0, 0, 0);
        }
        if (bv) {
          short4_t w0;
          #pragma unroll
          for (int r = 0; r < 4; ++r) {
            float h = -0.5f * acc0[r] + ((m0a + r == brow) ? 1.5f : 0.f);
            w0[r] = f2bf(h);
          }
          *(short4_t*)(bufB + brow * PADC + m0a) = w0;
          if (has2) {
            short4_t w1;
            #pragma unroll
            for (int r = 0; r < 4; ++r) {
              float h = -0.5f * acc1[r] + ((m1a + r == brow) ? 1.5f : 0.f);
              w1[r] = f2bf(h);
            }
            *(short4_t*)(bufB + brow * PADC + m1a) = w1;
          }
        }
      }
    }
    __syncthreads();
    {
      short8 g0[7], g1[7];
      #pragma unroll
      for (int ks = 0; ks < 7; ++ks) {
        int kk = ks * 32 + quad * 8;
        short8 v0 = s8zero(), v1 = s8zero();
        if (kk < PADC) {
          #pragma unroll
          for (int j = 0; j < 8; ++j) {
            v0[j] = bufA[(kk + j) * PADC + arow0];
            if (has2) v1[j] = bufA[(kk + j) * PADC + arow1];
          }
        }
        g0[ks] = v0; g1[ks] = v1;
      }
      __syncthreads();
      for (int ct = 0; ct < NTILE; ++ct) {
        int n = ct * 16 + ln15;
        bool nv = n < NTOK;
        f32x4 acc0 = {0.f, 0.f, 0.f, 0.f};
        f32x4 acc1 = {0.f, 0.f, 0.f, 0.f};
        #pragma unroll
        for (int ks = 0; ks < 7; ++ks) {
          int kk = ks * 32 + quad * 8;
          short8 bfr = (nv && kk < PADC) ? *(const short8*)(bufB + n * PADC + kk) : s8zero();
          acc0 = __builtin_amdgcn_mfma_f32_16x16x32_bf16(g0[ks], bfr, acc0, 0, 0, 0);
          if (has2)
            acc1 = __builtin_amdgcn_mfma_f32_16x16x32_bf16(g1[ks], bfr, acc1, 0, 0, 0);
        }
        if (nv) {
          short4_t w0;
          #pragma unroll
          for (int r = 0; r < 4; ++r) w0[r] = f2bf(acc0[r]);
          *(short4_t*)(bufA + n * PADC + m0a) = w0;
          if (has2) {
            short4_t w1;
            #pragma unroll
            for (int r = 0; r < 4; ++r) w1[r] = f2bf(acc1[r]);
            *(short4_t*)(bufA + n * PADC + m1a) = w1;
          }
        }
      }
    }
    __syncthreads();
  }

  for (int idx = tid; idx < MAT; idx += 512) {
    int i = idx / NTOK, j = idx - i * NTOK;
    XO[idx] = bf2f(bufA[i * PADC + j]);
  }
}

// ---------------- 196x196 transpose (LDS tiles) ----------------
__global__ void k_transpose(const float* __restrict__ Xb, float* __restrict__ Xt) {
  int b = blockIdx.y;
  int ti = blockIdx.x / 7, tj = blockIdx.x % 7;
  const float* X = Xb + (size_t)b * MAT;
  float* T = Xt + (size_t)b * MAT;
  __shared__ float ts[32][33];
  int tid = threadIdx.x;
  int r = tid >> 5, c = tid & 31;
  for (int rr = r; rr < 32; rr += 8) {
    int gi = ti * 32 + rr, gj = tj * 32 + c;
    ts[rr][c] = (gi < NTOK && gj < NTOK) ? X[gi * NTOK + gj] : 0.f;
  }
  __syncthreads();
  for (int rr = r; rr < 32; rr += 8) {
    int go = tj * 32 + rr, gc = ti * 32 + c;
    if (go < NTOK && gc < NTOK) T[go * NTOK + gc] = ts[c][rr];
  }
}

// ---------------- H = X X^T via split-bf16 MFMA, 2-way tile split ----------------
// grid (2, NB): half h owns lower-triangle tiles T in [h*46, h?91:46) -> 128 blocks.
__global__ __launch_bounds__(512, 1) void k_h_mfma(const float* __restrict__ Xb,
                                                   float* __restrict__ Hb) {
  extern __shared__ short hsm[];
  short* bhp = hsm;
  short* blp = hsm + HPLANE;
  int half = blockIdx.x, b = blockIdx.y;
  int Tbase = half * 46;
  int Tend = half ? 91 : 46;
  const float* X = Xb + (size_t)b * MAT;
  int tid = threadIdx.x;
  int wave = tid >> 6, ln15 = tid & 15, quad = (tid >> 4) & 3;

  for (int i = tid; i < 768; i += 512) {
    int p = i / 384, o = i - p * 384;
    ((int*)(hsm + p * HPLANE + 196 * HCH))[o] = 0;
  }
  __syncthreads();

  f32x4 zz = {0.f, 0.f, 0.f, 0.f};
  f32x4 acc[6];
  #pragma unroll
  for (int j = 0; j < 6; ++j) acc[j] = zz;

  for (int c = 0; c < 4; ++c) {
    int kc = c * HCH;
    bool full = (kc + HCH <= NTOK);
    for (int gi = tid; gi < NTOK * 8; gi += 512) {
      int r = gi >> 3, g = gi & 7;
      const float* sp = X + (size_t)r * NTOK + kc + g * 8;
      short8 hv = s8zero(), lv = s8zero();
      if (full) {
        float4 f0 = *(const float4*)(sp);
        float4 f1 = *(const float4*)(sp + 4);
        float vs[8] = {f0.x, f0.y, f0.z, f0.w, f1.x, f1.y, f1.z, f1.w};
        #pragma unroll
        for (int e = 0; e < 8; ++e) {
          short hb = f2bf(vs[e]);
          hv[e] = hb;
          lv[e] = f2bf(vs[e] - bf2f(hb));
        }
      } else {
        #pragma unroll
        for (int e = 0; e < 8; ++e) {
          int k = kc + g * 8 + e;
          if (k < NTOK) {
            float y = sp[e];
            short hb = f2bf(y);
            hv[e] = hb;
            lv[e] = f2bf(y - bf2f(hb));
          }
        }
      }
      int pg = (g ^ (r & 7)) * 8;
      *(short8*)(bhp + r * HCH + pg) = hv;
      *(short8*)(blp + r * HCH + pg) = lv;
    }
    __syncthreads();
    #pragma unroll
    for (int j = 0; j < 6; ++j) {
      int T = Tbase + wave + 8 * j;
      if (T < Tend) {
        int ti = (int)((sqrtf(8.f * T + 1.f) - 1.f) * 0.5f);
        if ((ti + 1) * (ti + 2) / 2 <= T) ++ti;
        if (ti * (ti + 1) / 2 > T) --ti;
        int tj = T - ti * (ti + 1) / 2;
        int ra = ti * 16 + ln15, rb = tj * 16 + ln15;
        #pragma unroll
        for (int ks = 0; ks < 2; ++ks) {
          int gb0 = ks * 4 + quad;
          int ga = (gb0 ^ (ra & 7)) * 8, gb = (gb0 ^ (rb & 7)) * 8;
          short8 ah = *(const short8*)(bhp + ra * HCH + ga);
          short8 al = *(const short8*)(blp + ra * HCH + ga);
          short8 bhf = *(const short8*)(bhp + rb * HCH + gb);
          short8 blf = *(const short8*)(blp + rb * HCH + gb);
          acc[j] = __builtin_amdgcn_mfma_f32_16x16x32_bf16(ah, bhf, acc[j], 0, 0, 0);
          acc[j] = __builtin_amdgcn_mfma_f32_16x16x32_bf16(ah, blf, acc[j], 0, 0, 0);
          acc[j] = __builtin_amdgcn_mfma_f32_16x16x32_bf16(al, bhf, acc[j], 0, 0, 0);
        }
      }
    }
    __syncthreads();
  }

  float* H = Hb + (size_t)b * MAT;
  #pragma unroll
  for (int j = 0; j < 6; ++j) {
    int T = Tbase + wave + 8 * j;
    if (T < Tend) {
      int ti = (int)((sqrtf(8.f * T + 1.f) - 1.f) * 0.5f);
      if ((ti + 1) * (ti + 2) / 2 <= T) ++ti;
      if (ti * (ti + 1) / 2 > T) --ti;
      int tj = T - ti * (ti + 1) / 2;
      int col = tj * 16 + ln15;
      #pragma unroll
      for (int r = 0; r < 4; ++r) {
        int row = ti * 16 + quad * 4 + r;
        if (row < NTOK && col < NTOK) {
          H[row * NTOK + col] = acc[j][r];
          if (ti != tj) H[col * NTOK + row] = acc[j][r];
        }
      }
    }
  }
}

// ---------------- Xn = 1.5 X - 0.5 H X via split-bf16 MFMA (k_F clone + axpy) ----------------
__global__ __launch_bounds__(512, 1) void k_nsup_mfma(
    const float* __restrict__ Hb, const float* __restrict__ Wb,
    const float* __restrict__ Xb, float* __restrict__ Xn,
    float* __restrict__ Wn, int writeW) {
  extern __shared__ short nsm[];
  short* Ah = nsm;
  short* Al = Ah + FAPLANE;
  short* Bh = Al + FAPLANE;
  short* Bl = Bh + FBPLANE;
  float* scr = (float*)(nsm + 2 * FAPLANE + 2 * FBPLANE);   // [8][16][17] floats
  int half = blockIdx.x, b = blockIdx.y;
  const float* H = Hb + (size_t)b * MAT;
  const float* W = Wb + (size_t)b * MAT;
  const float* X = Xb + (size_t)b * MAT;
  int co = half * 112;
  int tid = threadIdx.x;
  int wave = tid >> 6, ln15 = tid & 15, quad = (tid >> 4) & 3;

  f32x4 zz = {0.f, 0.f, 0.f, 0.f};
  f32x4 acc[12];
  #pragma unroll
  for (int j = 0; j < 12; ++j) acc[j] = zz;

  for (int c = 0; c < 4; ++c) {
    int kc = c * FCH;
    bool fullchunk = (kc + FCH <= NTOK);
    for (int gi = tid; gi < (FA_ROWS + FB_ROWS) * 8; gi += 512) {
      bool isA = gi < FA_ROWS * 8;
      int li = isA ? gi : gi - FA_ROWS * 8;
      int r = li >> 3, g = li & 7;
      int grow = isA ? r : co + r;
      short8 hv = s8zero(), lv = s8zero();
      if (grow < NTOK) {
        const float* src = (isA ? H : W) + (size_t)grow * NTOK + kc + g * 8;
        if (fullchunk) {
          float4 f0 = *(const float4*)(src);
          float4 f1 = *(const float4*)(src + 4);
          float vs[8] = {f0.x, f0.y, f0.z, f0.w, f1.x, f1.y, f1.z, f1.w};
          #pragma unroll
          for (int e = 0; e < 8; ++e) {
            short hb = f2bf(vs[e]);
            hv[e] = hb;
            lv[e] = f2bf(vs[e] - bf2f(hb));
          }
        } else {
          #pragma unroll
          for (int e = 0; e < 8; ++e) {
            int k = kc + g * 8 + e;
            if (k < NTOK) {
              float y = src[e];
              short hb = f2bf(y);
              hv[e] = hb;
              lv[e] = f2bf(y - bf2f(hb));
            }
          }
        }
      }
      int pg = (g ^ (r & 7)) * 8;
      if (isA) {
        *(short8*)(Ah + r * FCH + pg) = hv;
        *(short8*)(Al + r * FCH + pg) = lv;
      } else {
        *(short8*)(Bh + r * FCH + pg) = hv;
        *(short8*)(Bl + r * FCH + pg) = lv;
      }
    }
    __syncthreads();
    #pragma unroll
    for (int j = 0; j < 12; ++j) {
      int T = wave + 8 * j;
      if (T < 91) {
        int ti = T / 7, tj = T - ti * 7;
        if (co + tj * 16 < NTOK) {
          int ra = ti * 16 + ln15;
          int rb = tj * 16 + ln15;
          #pragma unroll
          for (int ks = 0; ks < 2; ++ks) {
            int gb0 = ks * 4 + quad;
            int ga = (gb0 ^ (ra & 7)) * 8, gb = (gb0 ^ (rb & 7)) * 8;
            short8 ah = *(const short8*)(Ah + ra * FCH + ga);
            short8 al = *(const short8*)(Al + ra * FCH + ga);
            short8 bh = *(const short8*)(Bh + rb * FCH + gb);
            short8 bl = *(const short8*)(Bl + rb * FCH + gb);
            acc[j] = __builtin_amdgcn_mfma_f32_16x16x32_bf16(ah, bh, acc[j], 0, 0, 0);
            acc[j] = __builtin_amdgcn_mfma_f32_16x16x32_bf16(ah, bl, acc[j], 0, 0, 0);
            acc[j] = __builtin_amdgcn_mfma_f32_16x16x32_bf16(al, bh, acc[j], 0, 0, 0);
          }
        }
      }
    }
    __syncthreads();
  }

  float* XnB = Xn + (size_t)b * MAT;
  float* WnB = writeW ? (Wn + (size_t)b * MAT) : (float*)0;
  float* ws = scr + wave * 16 * 17;
  #pragma unroll
  for (int j = 0; j < 12; ++j) {
    int T = wave + 8 * j;
    if (T < 91) {
      int ti = T / 7, tj = T - ti * 7;
      int colbase = co + tj * 16;
      if (colbase < NTOK) {
        int col = colbase + ln15;
        float vr[4];
        #pragma unroll
        for (int r = 0; r < 4; ++r) {
          int row = ti * 16 + quad * 4 + r;
          bool valid = (row < NTOK) && (col < NTOK);
          float v = valid ? (1.5f * X[row * NTOK + col] - 0.5f * acc[j][r]) : 0.f;
          vr[r] = v;
          if (valid) XnB[row * NTOK + col] = v;
        }
        if (writeW) {
          #pragma unroll
          for (int r = 0; r < 4; ++r) ws[ln15 * 17 + quad * 4 + r] = vr[r];
          #pragma unroll
          for (int rr = 0; rr < 4; ++rr) {
            int ro = colbase + quad * 4 + rr;     // Wn row = Xn col
            int cc = ti * 16 + ln15;              // Wn col = Xn row
            if (ro < NTOK && cc < NTOK)
              WnB[ro * NTOK + cc] = ws[(quad * 4 + rr) * 17 + ln15];
          }
        }
      }
    }
  }
}

// ---------------- Gp = X^T X (fp32, polish fallback) ----------------
__global__ void k_xtx(const float* __restrict__ Xb, float* __restrict__ Gp) {
  int b = blockIdx.y;
  const float* X = Xb + (size_t)b * MAT;
  int x = blockIdx.x, ti = 0;
  while (x >= ti + 1) { x -= ti + 1; ++ti; }
  int tj = x;
  int ri = ti * 32, cj = tj * 32;
  __shared__ float As[32][33], Bs[32][33];
  int tid = threadIdx.x, ty = tid >> 4, tx = tid & 15;
  float a00 = 0, a01 = 0, a10 = 0, a11 = 0;
  for (int k0 = 0; k0 < NTOK; k0 += 32) {
    for (int l = tid; l < 1024; l += 256) {
      int kk = l >> 5, ii = l & 31;
      int krow = k0 + kk;
      As[kk][ii] = (krow < NTOK && ri + ii < NTOK) ? X[(size_t)krow * NTOK + ri + ii] : 0.f;
      Bs[kk][ii] = (krow < NTOK && cj + ii < NTOK) ? X[(size_t)krow * NTOK + cj + ii] : 0.f;
    }
    __syncthreads();
    #pragma unroll
    for (int kk = 0; kk < 32; ++kk) {
      float p0 = As[kk][ty], p1 = As[kk][ty + 16];
      float q0 = Bs[kk][tx], q1 = Bs[kk][tx + 16];
      a00 += p0 * q0; a01 += p0 * q1; a10 += p1 * q0; a11 += p1 * q1;
    }
    __syncthreads();
  }
  float* G = Gp + (size_t)b * MAT;
  int i0 = ri + ty, i1 = ri + ty + 16, j0 = cj + tx, j1 = cj + tx + 16;
  if (i0 < NTOK && j0 < NTOK) { G[i0 * NTOK + j0] = a00; G[j0 * NTOK + i0] = a00; }
  if (i0 < NTOK && j1 < NTOK) { G[i0 * NTOK + j1] = a01; G[j1 * NTOK + i0] = a01; }
  if (i1 < NTOK && j0 < NTOK) { G[i1 * NTOK + j0] = a10; G[j0 * NTOK + i1] = a10; }
  if (i1 < NTOK && j1 < NTOK) { G[i1 * NTOK + j1] = a11; G[j1 * NTOK + i1] = a11; }
}

// ---------------- Xn = 1.5 X - 0.5 X * G (fp32, polish fallback) ----------------
__global__ void k_nsup(const float* __restrict__ Xb, const float* __restrict__ Gp,
                       float* __restrict__ Xn) {
  int b = blockIdx.y;
  const float* X = Xb + (size_t)b * MAT;
  const float* G = Gp + (size_t)b * MAT;
  int ti = blockIdx.x / 7, tj = blockIdx.x % 7;
  int ri = ti * 32, cj = tj * 32;
  __shared__ float As[32][33], Bs[32][33];
  int tid = threadIdx.x, ty = tid >> 4, tx = tid & 15;
  float a00 = 0, a01 = 0, a10 = 0, a11 = 0;
  for (int k0 = 0; k0 < NTOK; k0 += 32) {
    for (int l = tid; l < 1024; l += 256) {
      int rr = l >> 5, cc = l & 31;
      As[rr][cc] = (ri + rr < NTOK && k0 + cc < NTOK) ? X[(size_t)(ri + rr) * NTOK + k0 + cc] : 0.f;
      Bs[rr][cc] = (k0 + rr < NTOK && cj + cc < NTOK) ? G[(size_t)(k0 + rr) * NTOK + cj + cc] : 0.f;
    }
    __syncthreads();
    #pragma unroll
    for (int kk = 0; kk < 32; ++kk) {
      float p0 = As[ty][kk], p1 = As[ty + 16][kk];
      float q0 = Bs[kk][tx], q1 = Bs[kk][tx + 16];
      a00 += p0 * q0; a01 += p0 * q1; a10 += p1 * q0; a11 += p1 * q1;
    }
    __syncthreads();
  }
  float* O = Xn + (size_t)b * MAT;
  int i0 = ri + ty, i1 = ri + ty + 16, j0 = cj + tx, j1 = cj + tx + 16;
  if (i0 < NTOK && j0 < NTOK) O[i0 * NTOK + j0] = 1.5f * X[i0 * NTOK + j0] - 0.5f * a00;
  if (i0 < NTOK && j1 < NTOK) O[i0 * NTOK + j1] = 1.5f * X[i0 * NTOK + j1] - 0.5f * a01;
  if (i1 < NTOK && j0 < NTOK) O[i1 * NTOK + j0] = 1.5f * X[i1 * NTOK + j0] - 0.5f * a10;
  if (i1 < NTOK && j1 < NTOK) O[i1 * NTOK + j1] = 1.5f * X[i1 * NTOK + j1] - 0.5f * a11;
}

// ---------------- nuclear_b = sum(U .* F) ----------------
__global__ void k_nuc(const float* __restrict__ U, const float* __restrict__ Fbuf,
                      float* __restrict__ nucb) {
  int b = blockIdx.x;
  int tid = threadIdx.x;
  const float* Ub = U + (size_t)b * MAT;
  const float* Fb = Fbuf + (size_t)b * MAT;
  float acc = 0.f;
  for (int idx = tid; idx < MAT; idx += 256) acc += Ub[idx] * Fb[idx];
  __shared__ float red[256];
  red[tid] = acc;
  __syncthreads();
  for (int s = 128; s > 0; s >>= 1) { if (tid < s) red[tid] += red[tid + s]; __syncthreads(); }
  if (tid == 0) nucb[b] = red[0];
}

// ---------------- loss = mean_b relu(trP + trQ - 2*nuc) ----------------
__global__ void k_final(const float* __restrict__ trPb, const float* __restrict__ nucb,
                        float* __restrict__ out) {
  int tid = threadIdx.x;  // 64 threads = 1 wave
  float v = fmaxf(trPb[2 * tid] + trPb[2 * tid + 1] - 2.f * nucb[tid], 0.f);
  #pragma unroll
  for (int off = 32; off; off >>= 1) v += __shfl_down(v, off);
  if (tid == 0) out[0] = v * (1.f / 64.f);
}

extern "C" void kernel_launch(void* const* d_in, const int* in_sizes, int n_in,
                              void* d_out, int out_size, void* d_ws, size_t ws_size,
                              hipStream_t stream) {
  (void)in_sizes; (void)n_in; (void)out_size; (void)ws_size;
  const float* s = (const float*)d_in[0];
  const float* t = (const float*)d_in[1];
  const float* attn = (const float*)d_in[2];
  float* out = (float*)d_out;

  float* W = (float*)d_ws;
  float* Gbuf = W;                              // 128 * MAT   (G -> P -> L/LT, in place)
  float* Fbuf = Gbuf + (size_t)128 * MAT;       // 64 * MAT
  float* Xbuf = Fbuf + (size_t)64 * MAT;        // 64 * MAT
  float* Xnew = Xbuf + (size_t)64 * MAT;        // 64 * MAT
  float* Gpol = Xnew + (size_t)64 * MAT;        // 64 * MAT (H / polish scratch)
  float* Xt0  = Gpol + (size_t)64 * MAT;        // 64 * MAT (X^T)
  float* Xt1  = Xt0 + (size_t)64 * MAT;         // 64 * MAT (X1^T)
  float* wbuf = Xt1 + (size_t)64 * MAT;         // 64 * 196
  float* trPb = wbuf + (size_t)NB * NTOK;       // 128
  float* nucb = trPb + 128;                     // 64
  float* nrmb = nucb + 64;                      // 64

  k_w<<<NB, 256, 0, stream>>>(attn, wbuf);

  hipError_t gc_ok = hipFuncSetAttribute(
      reinterpret_cast<const void*>(k_gramc),
      hipFuncAttributeMaxDynamicSharedMemorySize, GC_LDS_BYTES);
  if (gc_ok == hipSuccess) {
    k_gramc<<<128, 512, GC_LDS_BYTES, stream>>>(s, t, wbuf, Gbuf, trPb);
  } else {
    k_gram_mfma<<<128, 512, GRAM_LDS_BYTES, stream>>>(s, t, wbuf, Gbuf);
    k_center<<<128, 256, 0, stream>>>(Gbuf, trPb);
  }

  hipError_t chol_ok = hipFuncSetAttribute(
      reinterpret_cast<const void*>(k_chol_panel),
      hipFuncAttributeMaxDynamicSharedMemorySize, CHOL2_LDS_BYTES);
  hipError_t fmf_ok = hipFuncSetAttribute(
      reinterpret_cast<const void*>(k_F_mfma),
      hipFuncAttributeMaxDynamicSharedMemorySize, FMF_LDS_BYTES);
  bool mfmaF = (chol_ok == hipSuccess) && (fmf_ok == hipSuccess);

  if (chol_ok == hipSuccess) {
    k_chol_panel<<<128, 256, CHOL2_LDS_BYTES, stream>>>(Gbuf, mfmaF ? 1 : 0);
  } else {
    k_chol_global<<<128, 256, 0, stream>>>(Gbuf);
  }

  if (mfmaF) {
    k_F_mfma<<<dim3(2, 64), 512, FMF_LDS_BYTES, stream>>>(Gbuf, Fbuf);
  } else {
    k_F<<<dim3(49, 64), 256, 0, stream>>>(Gbuf, Fbuf);
  }

  hipError_t pow_ok = hipFuncSetAttribute(
      reinterpret_cast<const void*>(k_pow_lds),
      hipFuncAttributeMaxDynamicSharedMemorySize, POW_LDS_BYTES);
  if (pow_ok == hipSuccess) {
    k_pow_lds<<<64, 256, POW_LDS_BYTES, stream>>>(Fbuf, nrmb);
  } else {
    k_pow<<<64, 256, 0, stream>>>(Fbuf, nrmb);
  }

  hipError_t fused_ok = hipFuncSetAttribute(
      reinterpret_cast<const void*>(k_polar_fused),
      hipFuncAttributeMaxDynamicSharedMemorySize, POLAR_LDS_BYTES);
  hipError_t h_ok = hipFuncSetAttribute(
      reinterpret_cast<const void*>(k_h_mfma),
      hipFuncAttributeMaxDynamicSharedMemorySize, H_LDS_BYTES);
  hipError_t ns_ok = hipFuncSetAttribute(
      reinterpret_cast<const void*>(k_nsup_mfma),
      hipFuncAttributeMaxDynamicSharedMemorySize, NS_LDS_BYTES);
  bool mfmaPolish = (h_ok == hipSuccess) && (ns_ok == hipSuccess);

  const float* finalX;
  if (fused_ok == hipSuccess) {
    // 15 bf16-MFMA iterations fused in one launch, then 2 polish iterations
    k_polar_fused<<<NB, 512, POLAR_LDS_BYTES, stream>>>(Fbuf, nrmb, Xbuf);
    if (mfmaPolish) {
      // polish via split-bf16 MFMA:  H = X X^T ;  Xn = 1.5X - 0.5 H X  (NT on W=X^T)
      k_transpose<<<dim3(49, 64), 256, 0, stream>>>(Xbuf, Xt0);
      k_h_mfma<<<dim3(2, 64), 512, H_LDS_BYTES, stream>>>(Xbuf, Gpol);
      k_nsup_mfma<<<dim3(2, 64), 512, NS_LDS_BYTES, stream>>>(Gpol, Xt0, Xbuf, Xnew, Xt1, 1);
      k_h_mfma<<<dim3(2, 64), 512, H_LDS_BYTES, stream>>>(Xnew, Gpol);
      k_nsup_mfma<<<dim3(2, 64), 512, NS_LDS_BYTES, stream>>>(Gpol, Xt1, Xnew, Xbuf, (float*)0, 0);
    } else {
      k_xtx<<<dim3(28, 64), 256, 0, stream>>>(Xbuf, Gpol);
      k_nsup<<<dim3(49, 64), 256, 0, stream>>>(Xbuf, Gpol, Xnew);
      k_xtx<<<dim3(28, 64), 256, 0, stream>>>(Xnew, Gpol);
      k_nsup<<<dim3(49, 64), 256, 0, stream>>>(Xnew, Gpol, Xbuf);
    }
    finalX = Xbuf;
  } else {
    // fallback: original fp32 loop
    k_scale<<<dim3(151, 64), 256, 0, stream>>>(Fbuf, nrmb, Xbuf);
    float* Xc = Xbuf;
    float* Xn = Xnew;
    for (int it = 0; it < POLAR_ITERS; ++it) {
      k_xtx<<<dim3(28, 64), 256, 0, stream>>>(Xc, Gpol);
      k_nsup<<<dim3(49, 64), 256, 0, stream>>>(Xc, Gpol, Xn);
      float* tmp = Xc; Xc = Xn; Xn = tmp;
    }
    finalX = Xc;
  }

  k_nuc<<<64, 256, 0, stream>>>(finalX, Fbuf, nucb);
  k_final<<<1, 64, 0, stream>>>(trPb, nucb, out);
}

// Round 10
// 868.198 us; speedup vs baseline: 1.2578x; 1.2578x over previous
//
#include <hip/hip_runtime.h>
#include <hip/hip_bf16.h>
#include <math.h>

#define NTOK 196
#define NDIM 768
#define NB 64
#define NH 12
#define NA 197               // N+1
#define MAT (NTOK * NTOK)    // 38416
#define ATTN_HW (NA * NA)    // 38809
#define POLAR_ITERS 15

// fused polar constants
#define PADC 208             // 13*16 padded cols/K for MFMA tiling
#define NTILE 13
// two buffers [196][208] bf16 = 163072 B (fits 160 KiB LDS)
#define POLAR_LDS_BYTES (2 * NTOK * PADC * 2)

// ---- MFMA gram constants ----
#define GCH 64               // K-chunk
#define GPLANE (208 * GCH)   // shorts per plane (rows padded to 208)
#define GRAM_LDS_BYTES (2 * GPLANE * 2)   // hi + lo planes = 53248 B

// ---- MFMA F constants (F = Lp^T Lq via LT rows, NT form) ----
#define FCH 64               // K-chunk (K padded 196 -> 256, 4 chunks)
#define FA_ROWS 208          // A rows (output i, padded)
#define FB_ROWS 112          // B rows per column-half (7 tiles x 16)
#define FAPLANE (FA_ROWS * FCH)
#define FBPLANE (FB_ROWS * FCH)
#define FMF_LDS_BYTES ((2 * FAPLANE + 2 * FBPLANE) * 2)   // 81920 B

// ---- MFMA polish constants ----
#define HCH 64
#define HPLANE (208 * HCH)
#define H_LDS_BYTES (2 * HPLANE * 2)                      // 53248 B
#define NS_SCR_BYTES (8 * 16 * 17 * 4)                    // per-wave transpose scratch
#define NS_LDS_BYTES (FMF_LDS_BYTES + NS_SCR_BYTES)       // 90624 B

// ---- LDS power-iteration constants ----
#define POW_LD 197
#define POW_F_WORDS (NTOK * POW_LD)                       // 38612
#define POW_LDS_BYTES ((POW_F_WORDS + 2 * NTOK + 256) * 4) // 157040 B

// ---- panel-blocked Cholesky LDS layout (words) ----
#define PTLD 208                          // padded trailing-row dim for Pt
#define TRI_WORDS 19306                   // 196*197/2
#define CHOL2_PT_WORDS (16 * PTLD)        // 3328  (16B-aligned rows)
#define CHOL2_TRI_OFF CHOL2_PT_WORDS      // 3328
#define CHOL2_ROWOFF_OFF (CHOL2_TRI_OFF + TRI_WORDS)   // 22634
#define CHOL2_PV_OFF 22832                // padded to 16B alignment
#define CHOL2_LDS_BYTES ((CHOL2_PV_OFF + 32) * 4)      // 91456 B

typedef __attribute__((ext_vector_type(8))) short short8;
typedef __attribute__((ext_vector_type(4))) short short4_t;
typedef __attribute__((ext_vector_type(4))) float f32x4;

__device__ inline short8 s8zero() { short8 z = {0,0,0,0,0,0,0,0}; return z; }

__device__ inline short f2bf(float f) {            // RNE fp32 -> bf16
  union { float f; unsigned u; } v; v.f = f;
  unsigned u = v.u;
  u += 0x7fffu + ((u >> 16) & 1u);
  return (short)(u >> 16);
}
__device__ inline float bf2f(short s) {
  union { unsigned u; float f; } v;
  v.u = ((unsigned)(unsigned short)s) << 16;
  return v.f;
}

// ---------------- w: CLS->patch attention, head-mean, normalized ----------------
__global__ void k_w(const float* __restrict__ attn, float* __restrict__ wbuf) {
  int b = blockIdx.x;
  int tid = threadIdx.x;
  __shared__ float red[256];
  float w0 = 0.f;
  if (tid < NTOK) {
    size_t base = (size_t)b * NH * ATTN_HW + 1 + tid;
    #pragma unroll
    for (int h = 0; h < NH; ++h) w0 += attn[base + (size_t)h * ATTN_HW];
    w0 *= (1.f / NH);
  }
  red[tid] = (tid < NTOK) ? w0 : 0.f;
  __syncthreads();
  for (int s = 128; s > 0; s >>= 1) { if (tid < s) red[tid] += red[tid + s]; __syncthreads(); }
  float S = red[0];
  if (tid < NTOK) wbuf[b * NTOK + tid] = w0 / (S + 1e-8f);
}

// ---------------- Gram via split-bf16 MFMA: G = (w.*X)(w.*X)^T ----------------
// (round-7 known-good form; round-8's center fusion regressed 3x — latency
//  serialization at 1 block/CU; do not re-fuse)
__global__ __launch_bounds__(512, 1) void k_gram_mfma(
    const float* __restrict__ s, const float* __restrict__ t,
    const float* __restrict__ wbuf, float* __restrict__ Gbuf) {
  extern __shared__ short gsm[];
  short* bhp = gsm;              // hi plane [208][GCH]
  short* blp = gsm + GPLANE;     // lo plane
  __shared__ float wsh[NTOK];
  int slot = blockIdx.x, b = slot >> 1, src = slot & 1;
  const float* X = (src ? t : s) + (size_t)b * NTOK * NDIM;
  int tid = threadIdx.x;
  int wave = tid >> 6, ln15 = tid & 15, quad = (tid >> 4) & 3;

  if (tid < NTOK) wsh[tid] = wbuf[b * NTOK + tid];
  for (int i = tid; i < 768; i += 512) {
    int p = i / 384, o = i - p * 384;
    ((int*)(gsm + p * GPLANE + 196 * GCH))[o] = 0;
  }
  __syncthreads();

  f32x4 zz = {0.f, 0.f, 0.f, 0.f};
  f32x4 acc[12];
  #pragma unroll
  for (int j = 0; j < 12; ++j) acc[j] = zz;

  for (int c = 0; c < NDIM / GCH; ++c) {
    int kc = c * GCH;
    for (int gi = tid; gi < NTOK * 8; gi += 512) {
      int r = gi >> 3, g = gi & 7;
      const float* sp = X + (size_t)r * NDIM + kc + g * 8;
      float4 f0 = *(const float4*)(sp);
      float4 f1 = *(const float4*)(sp + 4);
      float wv = wsh[r];
      float vs[8] = {f0.x, f0.y, f0.z, f0.w, f1.x, f1.y, f1.z, f1.w};
      short8 hv, lv;
      #pragma unroll
      for (int e = 0; e < 8; ++e) {
        float y = wv * vs[e];
        short hb = f2bf(y);
        hv[e] = hb;
        lv[e] = f2bf(y - bf2f(hb));
      }
      int pg = (g ^ (r & 7)) * 8;
      *(short8*)(bhp + r * GCH + pg) = hv;
      *(short8*)(blp + r * GCH + pg) = lv;
    }
    __syncthreads();
    #pragma unroll
    for (int j = 0; j < 12; ++j) {
      int T = wave + 8 * j;
      if (T < 91) {
        int ti = (int)((sqrtf(8.f * T + 1.f) - 1.f) * 0.5f);
        if ((ti + 1) * (ti + 2) / 2 <= T) ++ti;
        if (ti * (ti + 1) / 2 > T) --ti;
        int tj = T - ti * (ti + 1) / 2;
        int ra = ti * 16 + ln15, rb = tj * 16 + ln15;
        #pragma unroll
        for (int ks = 0; ks < 2; ++ks) {
          int gb0 = ks * 4 + quad;
          int ga = (gb0 ^ (ra & 7)) * 8, gb = (gb0 ^ (rb & 7)) * 8;
          short8 ah = *(const short8*)(bhp + ra * GCH + ga);
          short8 al = *(const short8*)(blp + ra * GCH + ga);
          short8 bhf = *(const short8*)(bhp + rb * GCH + gb);
          short8 blf = *(const short8*)(blp + rb * GCH + gb);
          acc[j] = __builtin_amdgcn_mfma_f32_16x16x32_bf16(ah, bhf, acc[j], 0, 0, 0);
          acc[j] = __builtin_amdgcn_mfma_f32_16x16x32_bf16(ah, blf, acc[j], 0, 0, 0);
          acc[j] = __builtin_amdgcn_mfma_f32_16x16x32_bf16(al, bhf, acc[j], 0, 0, 0);
        }
      }
    }
    __syncthreads();
  }

  float* G = Gbuf + (size_t)slot * MAT;
  #pragma unroll
  for (int j = 0; j < 12; ++j) {
    int T = wave + 8 * j;
    if (T < 91) {
      int ti = (int)((sqrtf(8.f * T + 1.f) - 1.f) * 0.5f);
      if ((ti + 1) * (ti + 2) / 2 <= T) ++ti;
      if (ti * (ti + 1) / 2 > T) --ti;
      int tj = T - ti * (ti + 1) / 2;
      int col = tj * 16 + ln15;
      #pragma unroll
      for (int r = 0; r < 4; ++r) {
        int row = ti * 16 + quad * 4 + r;
        if (row < NTOK && col < NTOK) {
          G[row * NTOK + col] = acc[j][r];
          if (ti != tj) G[col * NTOK + row] = acc[j][r];
        }
      }
    }
  }
}

// ---------------- double-center in place: P = J G J (+ridge), record trace ----------------
// 512 threads: column sums split over 2 row-halves (392 active, coalesced),
// centering update vectorized as float4.
__global__ __launch_bounds__(512) void k_center(float* __restrict__ Gbuf,
                                                float* __restrict__ trPb) {
  int slot = blockIdx.x;
  float* A = Gbuf + (size_t)slot * MAT;
  __shared__ float r[NTOK];
  __shared__ float red[512];
  __shared__ float gsh, dsh;
  int tid = threadIdx.x;
  // partial column sums: thread t<392 sums rows [half*98, half*98+98) of col c
  float part = 0.f;
  if (tid < 392) {
    int c = (tid < NTOK) ? tid : tid - NTOK;
    int m0 = (tid < NTOK) ? 0 : 98;
    const float* p = A + (size_t)m0 * NTOK + c;
    for (int m = 0; m < 98; ++m) part += p[(size_t)m * NTOK];
  }
  red[tid] = part;
  __syncthreads();
  float rc = (tid < NTOK) ? (red[tid] + red[tid + NTOK]) : 0.f;
  __syncthreads();
  float rcm = rc * (1.f / NTOK);
  red[tid] = rcm;                      // 0 for tid >= 196 (rc==0)
  if (tid < NTOK) r[tid] = rcm;
  __syncthreads();
  for (int st = 256; st > 0; st >>= 1) { if (tid < st) red[tid] += red[tid + st]; __syncthreads(); }
  float g = red[0] * (1.f / NTOK);
  float tv = (tid < NTOK) ? (A[tid * NTOK + tid] - 2.f * r[tid] + g) : 0.f;
  __syncthreads();
  red[tid] = tv;
  __syncthreads();
  for (int st = 256; st > 0; st >>= 1) { if (tid < st) red[tid] += red[tid + st]; __syncthreads(); }
  if (tid == 0) {
    float tr = red[0];
    trPb[slot] = tr;
    gsh = g;
    dsh = 1e-4f * fmaxf(tr, 0.f) * (1.f / NTOK);
  }
  __syncthreads();
  float gg = gsh, dd = dsh;
  // vectorized centering (NTOK % 4 == 0 so each float4 stays within one row)
  for (int q = tid; q < MAT / 4; q += 512) {
    int idx = q * 4;
    int n = idx / NTOK, m = idx - n * NTOK;
    float4 v = ((const float4*)A)[q];
    float rn = r[n];
    v.x += gg - rn - r[m + 0];
    v.y += gg - rn - r[m + 1];
    v.z += gg - rn - r[m + 2];
    v.w += gg - rn - r[m + 3];
    if (n == m) v.x += dd;
    else if (n == m + 1) v.y += dd;
    else if (n == m + 2) v.z += dd;
    else if (n == m + 3) v.w += dd;
    ((float4*)A)[q] = v;
  }
}

// ---------------- panel-blocked (NB=16) Cholesky, triangle-packed LDS ----------------
// transposeOut != 0: write back L^T for the MFMA k_F consumer.
__global__ __launch_bounds__(256, 1) void k_chol_panel(float* __restrict__ Gbuf,
                                                       int transposeOut) {
  extern __shared__ float smf[];
  float* Pt = smf;                              // [16][PTLD]
  float* tri = smf + CHOL2_TRI_OFF;             // TRI_WORDS
  int* rowoff = (int*)(smf + CHOL2_ROWOFF_OFF); // [196]
  float* pvb = smf + CHOL2_PV_OFF;              // [2][16], 16B aligned
  int slot = blockIdx.x;
  float* A = Gbuf + (size_t)slot * MAT;
  int tid = threadIdx.x;
  if (tid < NTOK) rowoff[tid] = tid * (tid + 1) / 2;
  __syncthreads();
  for (int idx = tid; idx < MAT; idx += 256) {
    int i = idx / NTOK, j = idx - i * NTOK;
    if (j <= i) tri[rowoff[i] + j] = A[idx];
  }
  __syncthreads();

  for (int k0 = 0; k0 < NTOK; k0 += 16) {
    int nb = (NTOK - k0 < 16) ? (NTOK - k0) : 16;
    int t = tid;
    int i = k0 + t;
    bool hasrow = (t < NTOK - k0);
    int ro = hasrow ? rowoff[i] : 0;

    float a[16];
    #pragma unroll
    for (int jj = 0; jj < 16; ++jj) a[jj] = 0.f;
    if (hasrow) {
      #pragma unroll
      for (int jj = 0; jj < 16; ++jj)
        if (jj < nb && k0 + jj <= i) a[jj] = tri[ro + k0 + jj];
    }

    #pragma unroll
    for (int jj = 0; jj < 16; ++jj) {
      bool cv = (jj < nb);
      if (cv && hasrow && t >= jj && t < nb) pvb[((jj & 1) << 4) + t] = a[jj];
      __syncthreads();
      if (cv && hasrow && t >= jj) {
        const float* pv = pvb + ((jj & 1) << 4);
        f32x4 p0 = *(const f32x4*)(pv);
        f32x4 p1 = *(const f32x4*)(pv + 4);
        f32x4 p2 = *(const f32x4*)(pv + 8);
        f32x4 p3 = *(const f32x4*)(pv + 12);
        float pvj = (jj < 4) ? p0[jj & 3] : (jj < 8) ? p1[jj & 3]
                   : (jj < 12) ? p2[jj & 3] : p3[jj & 3];
        float sq = sqrtf(fmaxf(pvj, 1e-20f));
        float pivinv = 1.f / sq;
        float v = a[jj] * pivinv;
        a[jj] = v;
        #pragma unroll
        for (int m = 0; m < 16; ++m) {
          if (m > jj) {
            float pvm = (m < 4) ? p0[m & 3] : (m < 8) ? p1[m & 3]
                       : (m < 12) ? p2[m & 3] : p3[m & 3];
            if (m < nb) a[m] -= v * (pvm * pivinv);
          }
        }
      }
    }

    if (hasrow) {
      #pragma unroll
      for (int jj = 0; jj < 16; ++jj)
        if (jj < nb && k0 + jj <= i) tri[ro + k0 + jj] = a[jj];
      if (t >= nb) {
        #pragma unroll
        for (int jj = 0; jj < 16; ++jj)
          if (jj < nb) Pt[jj * PTLD + i] = a[jj];
      }
    }
    __syncthreads();

    int k1 = k0 + nb;
    int nrem = NTOK - k1;
    if (nrem > 0) {
      int ntile = (nrem + 3) >> 2;
      int Ttot = ntile * (ntile + 1) / 2;
      for (int T = tid; T < Ttot; T += 256) {
        float disc = (2.f * ntile + 1.f) * (2.f * ntile + 1.f) - 8.f * (float)T;
        int tm = (int)((2.f * ntile + 1.f - sqrtf(fmaxf(disc, 0.f))) * 0.5f);
        if (tm > ntile - 1) tm = ntile - 1;
        if (tm < 0) tm = 0;
        #define FCOL(c) ((c) * ntile - (((c) * ((c) - 1)) >> 1))
        while (tm + 1 <= ntile - 1 && FCOL(tm + 1) <= T) ++tm;
        while (tm > 0 && FCOL(tm) > T) --tm;
        int ti = tm + (T - FCOL(tm));
        #undef FCOL
        int i0 = k1 + ti * 4, m0 = k1 + tm * 4;
        f32x4 acc0 = {0.f, 0.f, 0.f, 0.f};
        f32x4 acc1 = acc0, acc2 = acc0, acc3 = acc0;
        #pragma unroll
        for (int jj = 0; jj < 16; ++jj) {
          if (jj < nb) {
            f32x4 li = *(const f32x4*)(Pt + jj * PTLD + i0);
            f32x4 lm = *(const f32x4*)(Pt + jj * PTLD + m0);
            acc0 += lm * li[0];
            acc1 += lm * li[1];
            acc2 += lm * li[2];
            acc3 += lm * li[3];
          }
        }
        #define STORE_ROW(r, av)                                        \
          { int ii = i0 + (r);                                          \
            if (ii < NTOK) {                                            \
              int roi = rowoff[ii];                                     \
              if (m0 + 0 <= ii) tri[roi + m0 + 0] -= (av)[0];           \
              if (m0 + 1 <= ii) tri[roi + m0 + 1] -= (av)[1];           \
              if (m0 + 2 <= ii) tri[roi + m0 + 2] -= (av)[2];           \
              if (m0 + 3 <= ii) tri[roi + m0 + 3] -= (av)[3];           \
            } }
        STORE_ROW(0, acc0)
        STORE_ROW(1, acc1)
        STORE_ROW(2, acc2)
        STORE_ROW(3, acc3)
        #undef STORE_ROW
      }
    }
    __syncthreads();
  }

  if (transposeOut) {
    for (int idx = tid; idx < MAT; idx += 256) {
      int r2 = idx / NTOK, c2 = idx - r2 * NTOK;
      A[idx] = (r2 <= c2) ? tri[rowoff[c2] + r2] : 0.f;
    }
  } else {
    for (int idx = tid; idx < MAT; idx += 256) {
      int i = idx / NTOK, j = idx - i * NTOK;
      A[idx] = (j <= i) ? tri[rowoff[i] + j] : 0.f;
    }
  }
}

// ---------------- fallback: original global-memory Cholesky ----------------
__global__ void k_chol_global(float* __restrict__ Gbuf) {
  int slot = blockIdx.x;
  float* A = Gbuf + (size_t)slot * MAT;
  __shared__ float col[NTOK];
  __shared__ float piv;
  int tid = threadIdx.x;
  for (int k = 0; k < NTOK; ++k) {
    if (tid == 0) { float p = sqrtf(fmaxf(A[k * NTOK + k], 1e-20f)); A[k * NTOK + k] = p; piv = p; }
    __syncthreads();
    float inv = 1.f / piv;
    for (int i = k + 1 + tid; i < NTOK; i += 256) {
      float v = A[i * NTOK + k] * inv;
      A[i * NTOK + k] = v;
      col[i] = v;
    }
    for (int j = k + 1 + tid; j < NTOK; j += 256) A[k * NTOK + j] = 0.f;
    __syncthreads();
    int nrem = NTOK - 1 - k;
    int total = nrem * (nrem + 1) / 2;
    for (int tt = tid; tt < total; tt += 256) {
      int a = (int)((sqrtf(8.f * tt + 1.f) - 1.f) * 0.5f);
      while ((a + 1) * (a + 2) / 2 <= tt) ++a;
      while (a * (a + 1) / 2 > tt) --a;
      int bb = tt - a * (a + 1) / 2;
      int i = k + 1 + a, j = k + 1 + bb;
      A[i * NTOK + j] -= col[i] * col[j];
    }
    __syncthreads();
  }
}

// ---------------- F = Lp^T Lq via split-bf16 MFMA (inputs are L^T, NT form) ----------------
__global__ __launch_bounds__(512, 1) void k_F_mfma(const float* __restrict__ Gbuf,
                                                   float* __restrict__ Fbuf) {
  extern __shared__ short fsm[];
  short* Ah = fsm;
  short* Al = Ah + FAPLANE;
  short* Bh = Al + FAPLANE;
  short* Bl = Bh + FBPLANE;
  int half = blockIdx.x, b = blockIdx.y;
  const float* LTp = Gbuf + (size_t)(2 * b) * MAT;
  const float* LTq = Gbuf + (size_t)(2 * b + 1) * MAT;
  int co = half * 112;
  int tid = threadIdx.x;
  int wave = tid >> 6, ln15 = tid & 15, quad = (tid >> 4) & 3;

  f32x4 zz = {0.f, 0.f, 0.f, 0.f};
  f32x4 acc[12];
  #pragma unroll
  for (int j = 0; j < 12; ++j) acc[j] = zz;

  for (int c = 0; c < 4; ++c) {
    int kc = c * FCH;
    bool fullchunk = (kc + FCH <= NTOK);
    for (int gi = tid; gi < (FA_ROWS + FB_ROWS) * 8; gi += 512) {
      bool isA = gi < FA_ROWS * 8;
      int li = isA ? gi : gi - FA_ROWS * 8;
      int r = li >> 3, g = li & 7;
      int grow = isA ? r : co + r;
      short8 hv = s8zero(), lv = s8zero();
      if (grow < NTOK) {
        const float* src = (isA ? LTp : LTq) + (size_t)grow * NTOK + kc + g * 8;
        if (fullchunk) {
          float4 f0 = *(const float4*)(src);
          float4 f1 = *(const float4*)(src + 4);
          float vs[8] = {f0.x, f0.y, f0.z, f0.w, f1.x, f1.y, f1.z, f1.w};
          #pragma unroll
          for (int e = 0; e < 8; ++e) {
            short hb = f2bf(vs[e]);
            hv[e] = hb;
            lv[e] = f2bf(vs[e] - bf2f(hb));
          }
        } else {
          #pragma unroll
          for (int e = 0; e < 8; ++e) {
            int k = kc + g * 8 + e;
            if (k < NTOK) {
              float y = src[e];
              short hb = f2bf(y);
              hv[e] = hb;
              lv[e] = f2bf(y - bf2f(hb));
            }
          }
        }
      }
      int pg = (g ^ (r & 7)) * 8;
      if (isA) {
        *(short8*)(Ah + r * FCH + pg) = hv;
        *(short8*)(Al + r * FCH + pg) = lv;
      } else {
        *(short8*)(Bh + r * FCH + pg) = hv;
        *(short8*)(Bl + r * FCH + pg) = lv;
      }
    }
    __syncthreads();
    #pragma unroll
    for (int j = 0; j < 12; ++j) {
      int T = wave + 8 * j;
      if (T < 91) {
        int ti = T / 7, tj = T - ti * 7;
        if (co + tj * 16 < NTOK) {
          int ra = ti * 16 + ln15;
          int rb = tj * 16 + ln15;
          #pragma unroll
          for (int ks = 0; ks < 2; ++ks) {
            int gb0 = ks * 4 + quad;
            int ga = (gb0 ^ (ra & 7)) * 8, gb = (gb0 ^ (rb & 7)) * 8;
            short8 ah = *(const short8*)(Ah + ra * FCH + ga);
            short8 al = *(const short8*)(Al + ra * FCH + ga);
            short8 bh = *(const short8*)(Bh + rb * FCH + gb);
            short8 bl = *(const short8*)(Bl + rb * FCH + gb);
            acc[j] = __builtin_amdgcn_mfma_f32_16x16x32_bf16(ah, bh, acc[j], 0, 0, 0);
            acc[j] = __builtin_amdgcn_mfma_f32_16x16x32_bf16(ah, bl, acc[j], 0, 0, 0);
            acc[j] = __builtin_amdgcn_mfma_f32_16x16x32_bf16(al, bh, acc[j], 0, 0, 0);
          }
        }
      }
    }
    __syncthreads();
  }

  float* F = Fbuf + (size_t)b * MAT;
  #pragma unroll
  for (int j = 0; j < 12; ++j) {
    int T = wave + 8 * j;
    if (T < 91) {
      int ti = T / 7, tj = T - ti * 7;
      int col = co + tj * 16 + ln15;
      if (col < NTOK) {
        #pragma unroll
        for (int r = 0; r < 4; ++r) {
          int row = ti * 16 + quad * 4 + r;
          if (row < NTOK) F[row * NTOK + col] = acc[j][r];
        }
      }
    }
  }
}

// ---------------- fallback F = Lp^T * Lq (scalar, reads L) ----------------
__global__ void k_F(const float* __restrict__ Gbuf, float* __restrict__ Fbuf) {
  int b = blockIdx.y;
  const float* Lp = Gbuf + (size_t)(2 * b) * MAT;
  const float* Lq = Gbuf + (size_t)(2 * b + 1) * MAT;
  int ti = blockIdx.x / 7, tj = blockIdx.x % 7;
  int ri = ti * 32, cj = tj * 32;
  __shared__ float As[32][33], Bs[32][33];
  int tid = threadIdx.x, ty = tid >> 4, tx = tid & 15;
  float a00 = 0, a01 = 0, a10 = 0, a11 = 0;
  for (int k0 = 0; k0 < NTOK; k0 += 32) {
    for (int l = tid; l < 1024; l += 256) {
      int kk = l >> 5, ii = l & 31;
      int krow = k0 + kk;
      As[kk][ii] = (krow < NTOK && ri + ii < NTOK) ? Lp[(size_t)krow * NTOK + ri + ii] : 0.f;
      Bs[kk][ii] = (krow < NTOK && cj + ii < NTOK) ? Lq[(size_t)krow * NTOK + cj + ii] : 0.f;
    }
    __syncthreads();
    #pragma unroll
    for (int kk = 0; kk < 32; ++kk) {
      float p0 = As[kk][ty], p1 = As[kk][ty + 16];
      float q0 = Bs[kk][tx], q1 = Bs[kk][tx + 16];
      a00 += p0 * q0; a01 += p0 * q1; a10 += p1 * q0; a11 += p1 * q1;
    }
    __syncthreads();
  }
  float* F = Fbuf + (size_t)b * MAT;
  int i0 = ri + ty, i1 = ri + ty + 16, j0 = cj + tx, j1 = cj + tx + 16;
  if (i0 < NTOK && j0 < NTOK) F[i0 * NTOK + j0] = a00;
  if (i0 < NTOK && j1 < NTOK) F[i0 * NTOK + j1] = a01;
  if (i1 < NTOK && j0 < NTOK) F[i1 * NTOK + j0] = a10;
  if (i1 < NTOK && j1 < NTOK) F[i1 * NTOK + j1] = a11;
}

// ---------------- power iteration from LDS: sigma_max -> 1/(1.1*sigma) ----------------
__global__ __launch_bounds__(256, 1) void k_pow_lds(const float* __restrict__ Fbuf,
                                                    float* __restrict__ nrmb) {
  extern __shared__ float psm[];
  float* Fsh = psm;                 // [196][197]
  float* v = psm + POW_F_WORDS;
  float* u = v + NTOK;
  float* red = u + NTOK;
  int b = blockIdx.x;
  const float* F = Fbuf + (size_t)b * MAT;
  int tid = threadIdx.x;
  for (int idx = tid; idx < MAT; idx += 256) {
    int i = idx / NTOK, j = idx - i * NTOK;
    Fsh[i * POW_LD + j] = F[idx];
  }
  if (tid < NTOK) v[tid] = 1.f;
  __syncthreads();
  float lastsum = 1.f;
  for (int it = 0; it < 6; ++it) {
    if (tid < NTOK) {
      float a = 0.f;
      for (int j = 0; j < NTOK; ++j) a += Fsh[tid * POW_LD + j] * v[j];
      u[tid] = a;
    }
    __syncthreads();
    float a2 = 0.f;
    if (tid < NTOK) { for (int i = 0; i < NTOK; ++i) a2 += Fsh[i * POW_LD + tid] * u[i]; }
    red[tid] = (tid < NTOK) ? a2 * a2 : 0.f;
    __syncthreads();
    for (int s2 = 128; s2 > 0; s2 >>= 1) { if (tid < s2) red[tid] += red[tid + s2]; __syncthreads(); }
    float sum = red[0];
    lastsum = sum;
    float invn = rsqrtf(sum + 1e-30f);
    __syncthreads();
    if (tid < NTOK) v[tid] = a2 * invn;
    __syncthreads();
  }
  if (tid == 0) {
    float sig = sqrtf(sqrtf(lastsum));
    nrmb[b] = 1.f / (1.1f * sig + 1e-30f);
  }
}

// ---------------- fallback power iteration (global) ----------------
__global__ void k_pow(const float* __restrict__ Fbuf, float* __restrict__ nrmb) {
  int b = blockIdx.x;
  const float* F = Fbuf + (size_t)b * MAT;
  __shared__ float v[NTOK], u[NTOK];
  __shared__ float red[256];
  int tid = threadIdx.x;
  if (tid < NTOK) v[tid] = 1.f;
  __syncthreads();
  float lastsum = 1.f;
  for (int it = 0; it < 6; ++it) {
    float a = 0.f;
    if (tid < NTOK) { for (int j = 0; j < NTOK; ++j) a += F[tid * NTOK + j] * v[j]; }
    __syncthreads();
    if (tid < NTOK) u[tid] = a;
    __syncthreads();
    float a2 = 0.f;
    if (tid < NTOK) { for (int i = 0; i < NTOK; ++i) a2 += F[i * NTOK + tid] * u[i]; }
    red[tid] = (tid < NTOK) ? a2 * a2 : 0.f;
    __syncthreads();
    for (int s = 128; s > 0; s >>= 1) { if (tid < s) red[tid] += red[tid + s]; __syncthreads(); }
    float sum = red[0];
    lastsum = sum;
    float invn = rsqrtf(sum + 1e-30f);
    __syncthreads();
    if (tid < NTOK) v[tid] = a2 * invn;
    __syncthreads();
  }
  if (tid == 0) {
    float sig = sqrtf(sqrtf(lastsum));
    nrmb[b] = 1.f / (1.1f * sig + 1e-30f);
  }
}

// ---------------- X0 = F * invnorm (fallback path only) ----------------
__global__ void k_scale(const float* __restrict__ Fbuf, const float* __restrict__ nrmb,
                        float* __restrict__ X) {
  int b = blockIdx.y;
  int idx = blockIdx.x * 256 + threadIdx.x;
  if (idx < MAT) X[(size_t)b * MAT + idx] = Fbuf[(size_t)b * MAT + idx] * nrmb[b];
}

// ---------------- fused bf16-MFMA polar Newton-Schulz loop (all-LDS) ----------------
// EXACT round-2 structure (best measured).  Do not restructure (r3/r4/r5 all lost).
__global__ __launch_bounds__(512, 1) void k_polar_fused(
    const float* __restrict__ Fbuf, const float* __restrict__ nrmb,
    float* __restrict__ Xout) {
  extern __shared__ short sm[];
  short* bufA = sm;                      // [196][PADC]  X
  short* bufB = sm + NTOK * PADC;        // [196][PADC]  H'
  int b = blockIdx.x;
  const float* F = Fbuf + (size_t)b * MAT;
  float* XO = Xout + (size_t)b * MAT;
  int tid = threadIdx.x;
  int wave = tid >> 6, ln15 = tid & 15, quad = (tid >> 4) & 3;
  int rt0 = wave, rt1 = wave + 8;
  bool has2 = (rt1 < NTILE);

  for (int i = tid; i < (2 * NTOK * PADC) / 2; i += 512) ((int*)sm)[i] = 0;
  __syncthreads();
  float invc = nrmb[b];
  for (int idx = tid; idx < MAT; idx += 512) {
    int i = idx / NTOK, j = idx - i * NTOK;
    bufA[i * PADC + j] = f2bf(F[idx] * invc);
  }
  __syncthreads();

  int arow0 = rt0 * 16 + ln15;
  int arow1 = rt1 * 16 + ln15;
  bool av1 = has2 && (arow1 < NTOK);
  int m0a = rt0 * 16 + quad * 4;
  int m1a = rt1 * 16 + quad * 4;

  for (int it = 0; it < POLAR_ITERS; ++it) {
    {
      short8 a0[7], a1[7];
      #pragma unroll
      for (int ks = 0; ks < 7; ++ks) {
        int kk = ks * 32 + quad * 8;
        a0[ks] = (kk < PADC) ? *(const short8*)(bufA + arow0 * PADC + kk) : s8zero();
        a1[ks] = (av1 && kk < PADC) ? *(const short8*)(bufA + arow1 * PADC + kk) : s8zero();
      }
      for (int ct = 0; ct < NTILE; ++ct) {
        int brow = ct * 16 + ln15;
        bool bv = brow < NTOK;
        f32x4 acc0 = {0.f, 0.f, 0.f, 0.f};
        f32x4 acc1 = {0.f, 0.f, 0.f, 0.f};
        #pragma unroll
        for (int ks = 0; ks < 7; ++ks) {
          int kk = ks * 32 + quad * 8;
          short8 bfr = (bv && kk < PADC) ? *(const short8*)(bufA + brow * PADC + kk) : s8zero();
          acc0 = __builtin_amdgcn_mfma_f32_16x16x32_bf16(a0[ks], bfr, acc0, 0, 0, 0);
          if (has2)
            acc1 = __builtin_amdgcn_mfma_f32_16x16x32_bf16(a1[ks], bfr, acc1, 0, 0, 0);
        }
        if (bv) {
          short4_t w0;
          #pragma unroll
          for (int r = 0; r < 4; ++r) {
            float h = -0.5f * acc0[r] + ((m0a + r == brow) ? 1.5f : 0.f);
            w0[r] = f2bf(h);
          }
          *(short4_t*)(bufB + brow * PADC + m0a) = w0;
          if (has2) {
            short4_t w1;
            #pragma unroll
            for (int r = 0; r < 4; ++r) {
              float h = -0.5f * acc1[r] + ((m1a + r == brow) ? 1.5f : 0.f);
              w1[r] = f2bf(h);
            }
            *(short4_t*)(bufB + brow * PADC + m1a) = w1;
          }
        }
      }
    }
    __syncthreads();
    {
      short8 g0[7], g1[7];
      #pragma unroll
      for (int ks = 0; ks < 7; ++ks) {
        int kk = ks * 32 + quad * 8;
        short8 v0 = s8zero(), v1 = s8zero();
        if (kk < PADC) {
          #pragma unroll
          for (int j = 0; j < 8; ++j) {
            v0[j] = bufA[(kk + j) * PADC + arow0];
            if (has2) v1[j] = bufA[(kk + j) * PADC + arow1];
          }
        }
        g0[ks] = v0; g1[ks] = v1;
      }
      __syncthreads();
      for (int ct = 0; ct < NTILE; ++ct) {
        int n = ct * 16 + ln15;
        bool nv = n < NTOK;
        f32x4 acc0 = {0.f, 0.f, 0.f, 0.f};
        f32x4 acc1 = {0.f, 0.f, 0.f, 0.f};
        #pragma unroll
        for (int ks = 0; ks < 7; ++ks) {
          int kk = ks * 32 + quad * 8;
          short8 bfr = (nv && kk < PADC) ? *(const short8*)(bufB + n * PADC + kk) : s8zero();
          acc0 = __builtin_amdgcn_mfma_f32_16x16x32_bf16(g0[ks], bfr, acc0, 0, 0, 0);
          if (has2)
            acc1 = __builtin_amdgcn_mfma_f32_16x16x32_bf16(g1[ks], bfr, acc1, 0, 0, 0);
        }
        if (nv) {
          short4_t w0;
          #pragma unroll
          for (int r = 0; r < 4; ++r) w0[r] = f2bf(acc0[r]);
          *(short4_t*)(bufA + n * PADC + m0a) = w0;
          if (has2) {
            short4_t w1;
            #pragma unroll
            for (int r = 0; r < 4; ++r) w1[r] = f2bf(acc1[r]);
            *(short4_t*)(bufA + n * PADC + m1a) = w1;
          }
        }
      }
    }
    __syncthreads();
  }

  for (int idx = tid; idx < MAT; idx += 512) {
    int i = idx / NTOK, j = idx - i * NTOK;
    XO[idx] = bf2f(bufA[i * PADC + j]);
  }
}

// ---------------- 196x196 transpose (LDS tiles) ----------------
__global__ void k_transpose(const float* __restrict__ Xb, float* __restrict__ Xt) {
  int b = blockIdx.y;
  int ti = blockIdx.x / 7, tj = blockIdx.x % 7;
  const float* X = Xb + (size_t)b * MAT;
  float* T = Xt + (size_t)b * MAT;
  __shared__ float ts[32][33];
  int tid = threadIdx.x;
  int r = tid >> 5, c = tid & 31;
  for (int rr = r; rr < 32; rr += 8) {
    int gi = ti * 32 + rr, gj = tj * 32 + c;
    ts[rr][c] = (gi < NTOK && gj < NTOK) ? X[gi * NTOK + gj] : 0.f;
  }
  __syncthreads();
  for (int rr = r; rr < 32; rr += 8) {
    int go = tj * 32 + rr, gc = ti * 32 + c;
    if (go < NTOK && gc < NTOK) T[go * NTOK + gc] = ts[c][rr];
  }
}

// ---------------- H = X X^T via split-bf16 MFMA, 2-way tile split ----------------
__global__ __launch_bounds__(512, 1) void k_h_mfma(const float* __restrict__ Xb,
                                                   float* __restrict__ Hb) {
  extern __shared__ short hsm[];
  short* bhp = hsm;
  short* blp = hsm + HPLANE;
  int half = blockIdx.x, b = blockIdx.y;
  int Tbase = half * 46;
  int Tend = half ? 91 : 46;
  const float* X = Xb + (size_t)b * MAT;
  int tid = threadIdx.x;
  int wave = tid >> 6, ln15 = tid & 15, quad = (tid >> 4) & 3;

  for (int i = tid; i < 768; i += 512) {
    int p = i / 384, o = i - p * 384;
    ((int*)(hsm + p * HPLANE + 196 * HCH))[o] = 0;
  }
  __syncthreads();

  f32x4 zz = {0.f, 0.f, 0.f, 0.f};
  f32x4 acc[6];
  #pragma unroll
  for (int j = 0; j < 6; ++j) acc[j] = zz;

  for (int c = 0; c < 4; ++c) {
    int kc = c * HCH;
    bool full = (kc + HCH <= NTOK);
    for (int gi = tid; gi < NTOK * 8; gi += 512) {
      int r = gi >> 3, g = gi & 7;
      const float* sp = X + (size_t)r * NTOK + kc + g * 8;
      short8 hv = s8zero(), lv = s8zero();
      if (full) {
        float4 f0 = *(const float4*)(sp);
        float4 f1 = *(const float4*)(sp + 4);
        float vs[8] = {f0.x, f0.y, f0.z, f0.w, f1.x, f1.y, f1.z, f1.w};
        #pragma unroll
        for (int e = 0; e < 8; ++e) {
          short hb = f2bf(vs[e]);
          hv[e] = hb;
          lv[e] = f2bf(vs[e] - bf2f(hb));
        }
      } else {
        #pragma unroll
        for (int e = 0; e < 8; ++e) {
          int k = kc + g * 8 + e;
          if (k < NTOK) {
            float y = sp[e];
            short hb = f2bf(y);
            hv[e] = hb;
            lv[e] = f2bf(y - bf2f(hb));
          }
        }
      }
      int pg = (g ^ (r & 7)) * 8;
      *(short8*)(bhp + r * HCH + pg) = hv;
      *(short8*)(blp + r * HCH + pg) = lv;
    }
    __syncthreads();
    #pragma unroll
    for (int j = 0; j < 6; ++j) {
      int T = Tbase + wave + 8 * j;
      if (T < Tend) {
        int ti = (int)((sqrtf(8.f * T + 1.f) - 1.f) * 0.5f);
        if ((ti + 1) * (ti + 2) / 2 <= T) ++ti;
        if (ti * (ti + 1) / 2 > T) --ti;
        int tj = T - ti * (ti + 1) / 2;
        int ra = ti * 16 + ln15, rb = tj * 16 + ln15;
        #pragma unroll
        for (int ks = 0; ks < 2; ++ks) {
          int gb0 = ks * 4 + quad;
          int ga = (gb0 ^ (ra & 7)) * 8, gb = (gb0 ^ (rb & 7)) * 8;
          short8 ah = *(const short8*)(bhp + ra * HCH + ga);
          short8 al = *(const short8*)(blp + ra * HCH + ga);
          short8 bhf = *(const short8*)(bhp + rb * HCH + gb);
          short8 blf = *(const short8*)(blp + rb * HCH + gb);
          acc[j] = __builtin_amdgcn_mfma_f32_16x16x32_bf16(ah, bhf, acc[j], 0, 0, 0);
          acc[j] = __builtin_amdgcn_mfma_f32_16x16x32_bf16(ah, blf, acc[j], 0, 0, 0);
          acc[j] = __builtin_amdgcn_mfma_f32_16x16x32_bf16(al, bhf, acc[j], 0, 0, 0);
        }
      }
    }
    __syncthreads();
  }

  float* H = Hb + (size_t)b * MAT;
  #pragma unroll
  for (int j = 0; j < 6; ++j) {
    int T = Tbase + wave + 8 * j;
    if (T < Tend) {
      int ti = (int)((sqrtf(8.f * T + 1.f) - 1.f) * 0.5f);
      if ((ti + 1) * (ti + 2) / 2 <= T) ++ti;
      if (ti * (ti + 1) / 2 > T) --ti;
      int tj = T - ti * (ti + 1) / 2;
      int col = tj * 16 + ln15;
      #pragma unroll
      for (int r = 0; r < 4; ++r) {
        int row = ti * 16 + quad * 4 + r;
        if (row < NTOK && col < NTOK) {
          H[row * NTOK + col] = acc[j][r];
          if (ti != tj) H[col * NTOK + row] = acc[j][r];
        }
      }
    }
  }
}

// ---------------- Xn = 1.5 X - 0.5 H X via split-bf16 MFMA (k_F clone + axpy) ----------------
__global__ __launch_bounds__(512, 1) void k_nsup_mfma(
    const float* __restrict__ Hb, const float* __restrict__ Wb,
    const float* __restrict__ Xb, float* __restrict__ Xn,
    float* __restrict__ Wn, int writeW) {
  extern __shared__ short nsm[];
  short* Ah = nsm;
  short* Al = Ah + FAPLANE;
  short* Bh = Al + FAPLANE;
  short* Bl = Bh + FBPLANE;
  float* scr = (float*)(nsm + 2 * FAPLANE + 2 * FBPLANE);   // [8][16][17] floats
  int half = blockIdx.x, b = blockIdx.y;
  const float* H = Hb + (size_t)b * MAT;
  const float* W = Wb + (size_t)b * MAT;
  const float* X = Xb + (size_t)b * MAT;
  int co = half * 112;
  int tid = threadIdx.x;
  int wave = tid >> 6, ln15 = tid & 15, quad = (tid >> 4) & 3;

  f32x4 zz = {0.f, 0.f, 0.f, 0.f};
  f32x4 acc[12];
  #pragma unroll
  for (int j = 0; j < 12; ++j) acc[j] = zz;

  for (int c = 0; c < 4; ++c) {
    int kc = c * FCH;
    bool fullchunk = (kc + FCH <= NTOK);
    for (int gi = tid; gi < (FA_ROWS + FB_ROWS) * 8; gi += 512) {
      bool isA = gi < FA_ROWS * 8;
      int li = isA ? gi : gi - FA_ROWS * 8;
      int r = li >> 3, g = li & 7;
      int grow = isA ? r : co + r;
      short8 hv = s8zero(), lv = s8zero();
      if (grow < NTOK) {
        const float* src = (isA ? H : W) + (size_t)grow * NTOK + kc + g * 8;
        if (fullchunk) {
          float4 f0 = *(const float4*)(src);
          float4 f1 = *(const float4*)(src + 4);
          float vs[8] = {f0.x, f0.y, f0.z, f0.w, f1.x, f1.y, f1.z, f1.w};
          #pragma unroll
          for (int e = 0; e < 8; ++e) {
            short hb = f2bf(vs[e]);
            hv[e] = hb;
            lv[e] = f2bf(vs[e] - bf2f(hb));
          }
        } else {
          #pragma unroll
          for (int e = 0; e < 8; ++e) {
            int k = kc + g * 8 + e;
            if (k < NTOK) {
              float y = src[e];
              short hb = f2bf(y);
              hv[e] = hb;
              lv[e] = f2bf(y - bf2f(hb));
            }
          }
        }
      }
      int pg = (g ^ (r & 7)) * 8;
      if (isA) {
        *(short8*)(Ah + r * FCH + pg) = hv;
        *(short8*)(Al + r * FCH + pg) = lv;
      } else {
        *(short8*)(Bh + r * FCH + pg) = hv;
        *(short8*)(Bl + r * FCH + pg) = lv;
      }
    }
    __syncthreads();
    #pragma unroll
    for (int j = 0; j < 12; ++j) {
      int T = wave + 8 * j;
      if (T < 91) {
        int ti = T / 7, tj = T - ti * 7;
        if (co + tj * 16 < NTOK) {
          int ra = ti * 16 + ln15;
          int rb = tj * 16 + ln15;
          #pragma unroll
          for (int ks = 0; ks < 2; ++ks) {
            int gb0 = ks * 4 + quad;
            int ga = (gb0 ^ (ra & 7)) * 8, gb = (gb0 ^ (rb & 7)) * 8;
            short8 ah = *(const short8*)(Ah + ra * FCH + ga);
            short8 al = *(const short8*)(Al + ra * FCH + ga);
            short8 bh = *(const short8*)(Bh + rb * FCH + gb);
            short8 bl = *(const short8*)(Bl + rb * FCH + gb);
            acc[j] = __builtin_amdgcn_mfma_f32_16x16x32_bf16(ah, bh, acc[j], 0, 0, 0);
            acc[j] = __builtin_amdgcn_mfma_f32_16x16x32_bf16(ah, bl, acc[j], 0, 0, 0);
            acc[j] = __builtin_amdgcn_mfma_f32_16x16x32_bf16(al, bh, acc[j], 0, 0, 0);
          }
        }
      }
    }
    __syncthreads();
  }

  float* XnB = Xn + (size_t)b * MAT;
  float* WnB = writeW ? (Wn + (size_t)b * MAT) : (float*)0;
  float* ws = scr + wave * 16 * 17;
  #pragma unroll
  for (int j = 0; j < 12; ++j) {
    int T = wave + 8 * j;
    if (T < 91) {
      int ti = T / 7, tj = T - ti * 7;
      int colbase = co + tj * 16;
      if (colbase < NTOK) {
        int col = colbase + ln15;
        float vr[4];
        #pragma unroll
        for (int r = 0; r < 4; ++r) {
          int row = ti * 16 + quad * 4 + r;
          bool valid = (row < NTOK) && (col < NTOK);
          float v = valid ? (1.5f * X[row * NTOK + col] - 0.5f * acc[j][r]) : 0.f;
          vr[r] = v;
          if (valid) XnB[row * NTOK + col] = v;
        }
        if (writeW) {
          #pragma unroll
          for (int r = 0; r < 4; ++r) ws[ln15 * 17 + quad * 4 + r] = vr[r];
          #pragma unroll
          for (int rr = 0; rr < 4; ++rr) {
            int ro = colbase + quad * 4 + rr;     // Wn row = Xn col
            int cc = ti * 16 + ln15;              // Wn col = Xn row
            if (ro < NTOK && cc < NTOK)
              WnB[ro * NTOK + cc] = ws[(quad * 4 + rr) * 17 + ln15];
          }
        }
      }
    }
  }
}

// ---------------- Gp = X^T X (fp32, polish fallback) ----------------
__global__ void k_xtx(const float* __restrict__ Xb, float* __restrict__ Gp) {
  int b = blockIdx.y;
  const float* X = Xb + (size_t)b * MAT;
  int x = blockIdx.x, ti = 0;
  while (x >= ti + 1) { x -= ti + 1; ++ti; }
  int tj = x;
  int ri = ti * 32, cj = tj * 32;
  __shared__ float As[32][33], Bs[32][33];
  int tid = threadIdx.x, ty = tid >> 4, tx = tid & 15;
  float a00 = 0, a01 = 0, a10 = 0, a11 = 0;
  for (int k0 = 0; k0 < NTOK; k0 += 32) {
    for (int l = tid; l < 1024; l += 256) {
      int kk = l >> 5, ii = l & 31;
      int krow = k0 + kk;
      As[kk][ii] = (krow < NTOK && ri + ii < NTOK) ? X[(size_t)krow * NTOK + ri + ii] : 0.f;
      Bs[kk][ii] = (krow < NTOK && cj + ii < NTOK) ? X[(size_t)krow * NTOK + cj + ii] : 0.f;
    }
    __syncthreads();
    #pragma unroll
    for (int kk = 0; kk < 32; ++kk) {
      float p0 = As[kk][ty], p1 = As[kk][ty + 16];
      float q0 = Bs[kk][tx], q1 = Bs[kk][tx + 16];
      a00 += p0 * q0; a01 += p0 * q1; a10 += p1 * q0; a11 += p1 * q1;
    }
    __syncthreads();
  }
  float* G = Gp + (size_t)b * MAT;
  int i0 = ri + ty, i1 = ri + ty + 16, j0 = cj + tx, j1 = cj + tx + 16;
  if (i0 < NTOK && j0 < NTOK) { G[i0 * NTOK + j0] = a00; G[j0 * NTOK + i0] = a00; }
  if (i0 < NTOK && j1 < NTOK) { G[i0 * NTOK + j1] = a01; G[j1 * NTOK + i0] = a01; }
  if (i1 < NTOK && j0 < NTOK) { G[i1 * NTOK + j0] = a10; G[j0 * NTOK + i1] = a10; }
  if (i1 < NTOK && j1 < NTOK) { G[i1 * NTOK + j1] = a11; G[j1 * NTOK + i1] = a11; }
}

// ---------------- Xn = 1.5 X - 0.5 X * G (fp32, polish fallback) ----------------
__global__ void k_nsup(const float* __restrict__ Xb, const float* __restrict__ Gp,
                       float* __restrict__ Xn) {
  int b = blockIdx.y;
  const float* X = Xb + (size_t)b * MAT;
  const float* G = Gp + (size_t)b * MAT;
  int ti = blockIdx.x / 7, tj = blockIdx.x % 7;
  int ri = ti * 32, cj = tj * 32;
  __shared__ float As[32][33], Bs[32][33];
  int tid = threadIdx.x, ty = tid >> 4, tx = tid & 15;
  float a00 = 0, a01 = 0, a10 = 0, a11 = 0;
  for (int k0 = 0; k0 < NTOK; k0 += 32) {
    for (int l = tid; l < 1024; l += 256) {
      int rr = l >> 5, cc = l & 31;
      As[rr][cc] = (ri + rr < NTOK && k0 + cc < NTOK) ? X[(size_t)(ri + rr) * NTOK + k0 + cc] : 0.f;
      Bs[rr][cc] = (k0 + rr < NTOK && cj + cc < NTOK) ? G[(size_t)(k0 + rr) * NTOK + cj + cc] : 0.f;
    }
    __syncthreads();
    #pragma unroll
    for (int kk = 0; kk < 32; ++kk) {
      float p0 = As[ty][kk], p1 = As[ty + 16][kk];
      float q0 = Bs[kk][tx], q1 = Bs[kk][tx + 16];
      a00 += p0 * q0; a01 += p0 * q1; a10 += p1 * q0; a11 += p1 * q1;
    }
    __syncthreads();
  }
  float* O = Xn + (size_t)b * MAT;
  int i0 = ri + ty, i1 = ri + ty + 16, j0 = cj + tx, j1 = cj + tx + 16;
  if (i0 < NTOK && j0 < NTOK) O[i0 * NTOK + j0] = 1.5f * X[i0 * NTOK + j0] - 0.5f * a00;
  if (i0 < NTOK && j1 < NTOK) O[i0 * NTOK + j1] = 1.5f * X[i0 * NTOK + j1] - 0.5f * a01;
  if (i1 < NTOK && j0 < NTOK) O[i1 * NTOK + j0] = 1.5f * X[i1 * NTOK + j0] - 0.5f * a10;
  if (i1 < NTOK && j1 < NTOK) O[i1 * NTOK + j1] = 1.5f * X[i1 * NTOK + j1] - 0.5f * a11;
}

// ---------------- nuclear_b = sum(U .* F) ----------------
__global__ void k_nuc(const float* __restrict__ U, const float* __restrict__ Fbuf,
                      float* __restrict__ nucb) {
  int b = blockIdx.x;
  int tid = threadIdx.x;
  const float* Ub = U + (size_t)b * MAT;
  const float* Fb = Fbuf + (size_t)b * MAT;
  float acc = 0.f;
  for (int idx = tid; idx < MAT; idx += 256) acc += Ub[idx] * Fb[idx];
  __shared__ float red[256];
  red[tid] = acc;
  __syncthreads();
  for (int s = 128; s > 0; s >>= 1) { if (tid < s) red[tid] += red[tid + s]; __syncthreads(); }
  if (tid == 0) nucb[b] = red[0];
}

// ---------------- loss = mean_b relu(trP + trQ - 2*nuc) ----------------
__global__ void k_final(const float* __restrict__ trPb, const float* __restrict__ nucb,
                        float* __restrict__ out) {
  int tid = threadIdx.x;  // 64 threads = 1 wave
  float v = fmaxf(trPb[2 * tid] + trPb[2 * tid + 1] - 2.f * nucb[tid], 0.f);
  #pragma unroll
  for (int off = 32; off; off >>= 1) v += __shfl_down(v, off);
  if (tid == 0) out[0] = v * (1.f / 64.f);
}

extern "C" void kernel_launch(void* const* d_in, const int* in_sizes, int n_in,
                              void* d_out, int out_size, void* d_ws, size_t ws_size,
                              hipStream_t stream) {
  (void)in_sizes; (void)n_in; (void)out_size; (void)ws_size;
  const float* s = (const float*)d_in[0];
  const float* t = (const float*)d_in[1];
  const float* attn = (const float*)d_in[2];
  float* out = (float*)d_out;

  float* W = (float*)d_ws;
  float* Gbuf = W;                              // 128 * MAT   (G -> P -> L/LT, in place)
  float* Fbuf = Gbuf + (size_t)128 * MAT;       // 64 * MAT
  float* Xbuf = Fbuf + (size_t)64 * MAT;        // 64 * MAT
  float* Xnew = Xbuf + (size_t)64 * MAT;        // 64 * MAT
  float* Gpol = Xnew + (size_t)64 * MAT;        // 64 * MAT (H / polish scratch)
  float* Xt0  = Gpol + (size_t)64 * MAT;        // 64 * MAT (X^T)
  float* Xt1  = Xt0 + (size_t)64 * MAT;         // 64 * MAT (X1^T)
  float* wbuf = Xt1 + (size_t)64 * MAT;         // 64 * 196
  float* trPb = wbuf + (size_t)NB * NTOK;       // 128
  float* nucb = trPb + 128;                     // 64
  float* nrmb = nucb + 64;                      // 64

  k_w<<<NB, 256, 0, stream>>>(attn, wbuf);
  k_gram_mfma<<<128, 512, GRAM_LDS_BYTES, stream>>>(s, t, wbuf, Gbuf);
  k_center<<<128, 512, 0, stream>>>(Gbuf, trPb);

  hipError_t chol_ok = hipFuncSetAttribute(
      reinterpret_cast<const void*>(k_chol_panel),
      hipFuncAttributeMaxDynamicSharedMemorySize, CHOL2_LDS_BYTES);
  hipError_t fmf_ok = hipFuncSetAttribute(
      reinterpret_cast<const void*>(k_F_mfma),
      hipFuncAttributeMaxDynamicSharedMemorySize, FMF_LDS_BYTES);
  bool mfmaF = (chol_ok == hipSuccess) && (fmf_ok == hipSuccess);

  if (chol_ok == hipSuccess) {
    k_chol_panel<<<128, 256, CHOL2_LDS_BYTES, stream>>>(Gbuf, mfmaF ? 1 : 0);
  } else {
    k_chol_global<<<128, 256, 0, stream>>>(Gbuf);
  }

  if (mfmaF) {
    k_F_mfma<<<dim3(2, 64), 512, FMF_LDS_BYTES, stream>>>(Gbuf, Fbuf);
  } else {
    k_F<<<dim3(49, 64), 256, 0, stream>>>(Gbuf, Fbuf);
  }

  hipError_t pow_ok = hipFuncSetAttribute(
      reinterpret_cast<const void*>(k_pow_lds),
      hipFuncAttributeMaxDynamicSharedMemorySize, POW_LDS_BYTES);
  if (pow_ok == hipSuccess) {
    k_pow_lds<<<64, 256, POW_LDS_BYTES, stream>>>(Fbuf, nrmb);
  } else {
    k_pow<<<64, 256, 0, stream>>>(Fbuf, nrmb);
  }

  hipError_t fused_ok = hipFuncSetAttribute(
      reinterpret_cast<const void*>(k_polar_fused),
      hipFuncAttributeMaxDynamicSharedMemorySize, POLAR_LDS_BYTES);
  hipError_t h_ok = hipFuncSetAttribute(
      reinterpret_cast<const void*>(k_h_mfma),
      hipFuncAttributeMaxDynamicSharedMemorySize, H_LDS_BYTES);
  hipError_t ns_ok = hipFuncSetAttribute(
      reinterpret_cast<const void*>(k_nsup_mfma),
      hipFuncAttributeMaxDynamicSharedMemorySize, NS_LDS_BYTES);
  bool mfmaPolish = (h_ok == hipSuccess) && (ns_ok == hipSuccess);

  const float* finalX;
  if (fused_ok == hipSuccess) {
    // 15 bf16-MFMA iterations fused in one launch, then 2 polish iterations
    k_polar_fused<<<NB, 512, POLAR_LDS_BYTES, stream>>>(Fbuf, nrmb, Xbuf);
    if (mfmaPolish) {
      // polish via split-bf16 MFMA:  H = X X^T ;  Xn = 1.5X - 0.5 H X  (NT on W=X^T)
      k_transpose<<<dim3(49, 64), 256, 0, stream>>>(Xbuf, Xt0);
      k_h_mfma<<<dim3(2, 64), 512, H_LDS_BYTES, stream>>>(Xbuf, Gpol);
      k_nsup_mfma<<<dim3(2, 64), 512, NS_LDS_BYTES, stream>>>(Gpol, Xt0, Xbuf, Xnew, Xt1, 1);
      k_h_mfma<<<dim3(2, 64), 512, H_LDS_BYTES, stream>>>(Xnew, Gpol);
      k_nsup_mfma<<<dim3(2, 64), 512, NS_LDS_BYTES, stream>>>(Gpol, Xt1, Xnew, Xbuf, (float*)0, 0);
    } else {
      k_xtx<<<dim3(28, 64), 256, 0, stream>>>(Xbuf, Gpol);
      k_nsup<<<dim3(49, 64), 256, 0, stream>>>(Xbuf, Gpol, Xnew);
      k_xtx<<<dim3(28, 64), 256, 0, stream>>>(Xnew, Gpol);
      k_nsup<<<dim3(49, 64), 256, 0, stream>>>(Xnew, Gpol, Xbuf);
    }
    finalX = Xbuf;
  } else {
    // fallback: original fp32 loop
    k_scale<<<dim3(151, 64), 256, 0, stream>>>(Fbuf, nrmb, Xbuf);
    float* Xc = Xbuf;
    float* Xn = Xnew;
    for (int it = 0; it < POLAR_ITERS; ++it) {
      k_xtx<<<dim3(28, 64), 256, 0, stream>>>(Xc, Gpol);
      k_nsup<<<dim3(49, 64), 256, 0, stream>>>(Xc, Gpol, Xn);
      float* tmp = Xc; Xc = Xn; Xn = tmp;
    }
    finalX = Xc;
  }

  k_nuc<<<64, 256, 0, stream>>>(finalX, Fbuf, nucb);
  k_final<<<1, 64, 0, stream>>>(trPb, nucb, out);
}